// Round 1
// baseline (1206.041 us; speedup 1.0000x reference)
//
#include <hip/hip_runtime.h>

typedef long long i64;

#define FULL 512
#define NBC  24   // B*C = 8*3

// ---------------------------------------------------------------- add3
__global__ __launch_bounds__(256) void add3_kernel(const float4* __restrict__ a,
                                                   const float4* __restrict__ b,
                                                   const float4* __restrict__ c,
                                                   float4* __restrict__ o, int n4) {
  int i = blockIdx.x * 256 + threadIdx.x;
  int stride = gridDim.x * 256;
  for (; i < n4; i += stride) {
    float4 x = a[i], y = b[i], z = c[i];
    o[i] = make_float4(x.x + y.x + z.x, x.y + y.y + z.y,
                       x.z + y.z + z.z, x.w + y.w + z.w);
  }
}

// ---------------------------------------------------------------- generic fp32 GEMM
// C[z] (512 x N) = A[z/aDiv] (512 x K) @ B[z%bMod] (K x N) (+ bias[z%biasMod])
__global__ __launch_bounds__(256) void gemm_f32(const float* __restrict__ A,
                                                const float* __restrict__ B,
                                                const float* __restrict__ bias,
                                                float* __restrict__ C,
                                                int N, int K,
                                                int aDiv, i64 aStride,
                                                int bMod, i64 bStride,
                                                int biasMod) {
  int z = blockIdx.z;
  const float* Ab = A + (i64)(z / aDiv) * aStride;
  const float* Bb = B + (i64)(z % bMod) * bStride;
  float* Cb = C + (i64)z * FULL * N;

  __shared__ float sA[16][68];
  __shared__ float sB[16][64];

  int tid = threadIdx.x;
  int tx = tid & 15, ty = tid >> 4;
  int m0 = blockIdx.y * 64, n0 = blockIdx.x * 64;

  float acc[4][4] = {};

  for (int k0 = 0; k0 < K; k0 += 16) {
    __syncthreads();
    // A tile 64x16 -> sA[k][m] (transposed)
    #pragma unroll
    for (int it = 0; it < 4; ++it)
      sA[tx][ty + it * 16] = Ab[(i64)(m0 + ty + it * 16) * K + (k0 + tx)];
    // B tile 16x64 -> sB[k][n]
    #pragma unroll
    for (int it = 0; it < 4; ++it) {
      int idx = tid + it * 256;
      int br = idx >> 6, bcn = idx & 63;
      sB[br][bcn] = Bb[(i64)(k0 + br) * N + (n0 + bcn)];
    }
    __syncthreads();
    #pragma unroll
    for (int k = 0; k < 16; ++k) {
      float4 a4 = *(const float4*)&sA[k][ty * 4];
      float4 b4 = *(const float4*)&sB[k][tx * 4];
      float av[4] = {a4.x, a4.y, a4.z, a4.w};
      float bv[4] = {b4.x, b4.y, b4.z, b4.w};
      #pragma unroll
      for (int i = 0; i < 4; ++i)
        #pragma unroll
        for (int j = 0; j < 4; ++j)
          acc[i][j] += av[i] * bv[j];
    }
  }

  #pragma unroll
  for (int i = 0; i < 4; ++i) {
    int m = m0 + ty * 4 + i;
    float4 v;
    float* vp = (float*)&v;
    #pragma unroll
    for (int j = 0; j < 4; ++j) {
      float t = acc[i][j];
      if (bias) t += bias[(i64)(z % biasMod) * N + n0 + tx * 4 + j];
      vp[j] = t;
    }
    *(float4*)&Cb[(i64)m * N + n0 + tx * 4] = v;
  }
}

// ---------------------------------------------------------------- M = key^T @ Wpi  (per bc,h -> 64x64)
__global__ __launch_bounds__(256) void mh_kernel(const float* __restrict__ key,
                                                 const float* __restrict__ Wpi,
                                                 float* __restrict__ M) {
  int z = blockIdx.x, h = z & 7;
  const float* Kb = key + (i64)z * FULL * 64;
  const float* Wb = Wpi + (i64)h * FULL * 64;
  float* Mb = M + (i64)z * 64 * 64;

  __shared__ float sK[64][68];
  __shared__ float sW[64][68];

  int tid = threadIdx.x, tx = tid & 15, ty = tid >> 4;
  float acc[4][4] = {};

  for (int s0 = 0; s0 < FULL; s0 += 64) {
    __syncthreads();
    #pragma unroll
    for (int it = 0; it < 4; ++it) {
      int idx = tid + it * 256;
      int r = idx >> 4, c4 = idx & 15;
      *(float4*)&sK[r][c4 * 4] = *(const float4*)&Kb[(i64)(s0 + r) * 64 + c4 * 4];
      *(float4*)&sW[r][c4 * 4] = *(const float4*)&Wb[(i64)(s0 + r) * 64 + c4 * 4];
    }
    __syncthreads();
    for (int s = 0; s < 64; ++s) {
      float4 a4 = *(const float4*)&sK[s][ty * 4];
      float4 b4 = *(const float4*)&sW[s][tx * 4];
      float av[4] = {a4.x, a4.y, a4.z, a4.w};
      float bv[4] = {b4.x, b4.y, b4.z, b4.w};
      #pragma unroll
      for (int i = 0; i < 4; ++i)
        #pragma unroll
        for (int j = 0; j < 4; ++j)
          acc[i][j] += av[i] * bv[j];
    }
  }
  #pragma unroll
  for (int i = 0; i < 4; ++i)
    #pragma unroll
    for (int j = 0; j < 4; ++j)
      Mb[(ty * 4 + i) * 64 + tx * 4 + j] = acc[i][j];
}

// ---------------------------------------------------------------- q2 = 0.125*pos@M + bpi  (in place over pos)
__global__ __launch_bounds__(256) void q2_kernel(float* __restrict__ posq2,
                                                 const float* __restrict__ M,
                                                 const float* __restrict__ bpi) {
  int z = blockIdx.y, h = z & 7;
  int t0 = blockIdx.x * 64;
  float* Pb = posq2 + ((i64)z * FULL + t0) * 64;
  const float* Mb = M + (i64)z * 4096;

  __shared__ float sP[64][68];
  __shared__ float sM[64][68];

  int tid = threadIdx.x, tx = tid & 15, ty = tid >> 4;
  #pragma unroll
  for (int it = 0; it < 4; ++it) {
    int idx = tid + it * 256;
    int r = idx >> 4, c4 = idx & 15;
    *(float4*)&sP[r][c4 * 4] = *(const float4*)&Pb[(i64)r * 64 + c4 * 4];
    *(float4*)&sM[r][c4 * 4] = *(const float4*)&Mb[(i64)r * 64 + c4 * 4];
  }
  __syncthreads();

  float acc[4][4] = {};
  for (int e = 0; e < 64; ++e) {
    float av[4];
    #pragma unroll
    for (int i = 0; i < 4; ++i) av[i] = sP[ty * 4 + i][e];
    float4 b4 = *(const float4*)&sM[e][tx * 4];
    float bv[4] = {b4.x, b4.y, b4.z, b4.w};
    #pragma unroll
    for (int i = 0; i < 4; ++i)
      #pragma unroll
      for (int j = 0; j < 4; ++j)
        acc[i][j] += av[i] * bv[j];
  }
  __syncthreads();
  #pragma unroll
  for (int i = 0; i < 4; ++i) {
    float4 v;
    float* vp = (float*)&v;
    #pragma unroll
    for (int j = 0; j < 4; ++j)
      vp[j] = 0.125f * acc[i][j] + bpi[h * 64 + tx * 4 + j];
    *(float4*)&Pb[(i64)(ty * 4 + i) * 64 + tx * 4] = v;
  }
}

// ---------------------------------------------------------------- flash attention (causal)
// Q,K,V: [24,8,512,64]; out: [24,512, h*64+d]
__global__ __launch_bounds__(256) void attn_kernel(const float* __restrict__ Q,
                                                   const float* __restrict__ K,
                                                   const float* __restrict__ V,
                                                   float* __restrict__ out) {
  int z = blockIdx.y, qt = blockIdx.x;
  int bc = z >> 3, h = z & 7;
  const float* Qb = Q + ((i64)z * FULL + qt * 64) * 64;
  const float* Kb = K + (i64)z * FULL * 64;
  const float* Vb = V + (i64)z * FULL * 64;

  __shared__ float sQ[64][68];
  __shared__ float sK[64][68];
  __shared__ float sV[64][68];
  __shared__ float sP[64][68];

  int tid = threadIdx.x, tx = tid & 15, ty = tid >> 4;

  #pragma unroll
  for (int it = 0; it < 4; ++it) {
    int idx = tid + it * 256;
    int r = idx >> 4, c4 = idx & 15;
    *(float4*)&sQ[r][c4 * 4] = *(const float4*)&Qb[(i64)r * 64 + c4 * 4];
  }

  float m_i[4], l_i[4], acc[4][4] = {};
  #pragma unroll
  for (int i = 0; i < 4; ++i) { m_i[i] = -3e38f; l_i[i] = 0.f; }

  for (int st = 0; st <= qt; ++st) {
    __syncthreads();
    #pragma unroll
    for (int it = 0; it < 4; ++it) {
      int idx = tid + it * 256;
      int r = idx >> 4, c4 = idx & 15;
      *(float4*)&sK[r][c4 * 4] = *(const float4*)&Kb[((i64)st * 64 + r) * 64 + c4 * 4];
      *(float4*)&sV[r][c4 * 4] = *(const float4*)&Vb[((i64)st * 64 + r) * 64 + c4 * 4];
    }
    __syncthreads();

    float s[4][4] = {};
    for (int d4 = 0; d4 < 16; ++d4) {
      float4 q4[4], k4[4];
      #pragma unroll
      for (int i = 0; i < 4; ++i) q4[i] = *(const float4*)&sQ[ty * 4 + i][d4 * 4];
      #pragma unroll
      for (int j = 0; j < 4; ++j) k4[j] = *(const float4*)&sK[tx * 4 + j][d4 * 4];
      #pragma unroll
      for (int i = 0; i < 4; ++i) {
        float qa[4] = {q4[i].x, q4[i].y, q4[i].z, q4[i].w};
        #pragma unroll
        for (int j = 0; j < 4; ++j) {
          float ka[4] = {k4[j].x, k4[j].y, k4[j].z, k4[j].w};
          s[i][j] += qa[0]*ka[0] + qa[1]*ka[1] + qa[2]*ka[2] + qa[3]*ka[3];
        }
      }
    }
    #pragma unroll
    for (int i = 0; i < 4; ++i)
      #pragma unroll
      for (int j = 0; j < 4; ++j)
        s[i][j] *= 0.125f;

    if (st == qt) {
      #pragma unroll
      for (int i = 0; i < 4; ++i)
        #pragma unroll
        for (int j = 0; j < 4; ++j)
          if (tx * 4 + j > ty * 4 + i) s[i][j] = -3e38f;
    }

    float rm[4];
    #pragma unroll
    for (int i = 0; i < 4; ++i)
      rm[i] = fmaxf(fmaxf(s[i][0], s[i][1]), fmaxf(s[i][2], s[i][3]));
    #pragma unroll
    for (int off = 8; off >= 1; off >>= 1)
      #pragma unroll
      for (int i = 0; i < 4; ++i)
        rm[i] = fmaxf(rm[i], __shfl_xor(rm[i], off, 64));

    float alpha[4], p[4][4], rs[4];
    #pragma unroll
    for (int i = 0; i < 4; ++i) {
      float mn = fmaxf(m_i[i], rm[i]);
      alpha[i] = __expf(m_i[i] - mn);
      m_i[i] = mn;
      rs[i] = 0.f;
      #pragma unroll
      for (int j = 0; j < 4; ++j) {
        p[i][j] = __expf(s[i][j] - mn);
        rs[i] += p[i][j];
      }
    }
    #pragma unroll
    for (int off = 8; off >= 1; off >>= 1)
      #pragma unroll
      for (int i = 0; i < 4; ++i)
        rs[i] += __shfl_xor(rs[i], off, 64);
    #pragma unroll
    for (int i = 0; i < 4; ++i) {
      l_i[i] = l_i[i] * alpha[i] + rs[i];
      #pragma unroll
      for (int j = 0; j < 4; ++j) acc[i][j] *= alpha[i];
    }

    #pragma unroll
    for (int i = 0; i < 4; ++i)
      #pragma unroll
      for (int j = 0; j < 4; ++j)
        sP[ty * 4 + i][tx * 4 + j] = p[i][j];
    __syncthreads();

    for (int s4 = 0; s4 < 16; ++s4) {
      float4 p4[4], v4[4];
      #pragma unroll
      for (int i = 0; i < 4; ++i) p4[i] = *(const float4*)&sP[ty * 4 + i][s4 * 4];
      #pragma unroll
      for (int k = 0; k < 4; ++k) v4[k] = *(const float4*)&sV[s4 * 4 + k][tx * 4];
      #pragma unroll
      for (int i = 0; i < 4; ++i) {
        float pa[4] = {p4[i].x, p4[i].y, p4[i].z, p4[i].w};
        #pragma unroll
        for (int k = 0; k < 4; ++k) {
          float va[4] = {v4[k].x, v4[k].y, v4[k].z, v4[k].w};
          #pragma unroll
          for (int j = 0; j < 4; ++j)
            acc[i][j] += pa[k] * va[j];
        }
      }
    }
  }

  #pragma unroll
  for (int i = 0; i < 4; ++i) {
    float inv = 1.f / l_i[i];
    int t = qt * 64 + ty * 4 + i;
    float4 v;
    float* vp = (float*)&v;
    #pragma unroll
    for (int j = 0; j < 4; ++j) vp[j] = acc[i][j] * inv;
    *(float4*)&out[((i64)bc * FULL + t) * FULL + h * 64 + tx * 4] = v;
  }
}

// ---------------------------------------------------------------- launch
extern "C" void kernel_launch(void* const* d_in, const int* in_sizes, int n_in,
                              void* d_out, int out_size, void* d_ws, size_t ws_size,
                              hipStream_t stream) {
  const float* idx_i  = (const float*)d_in[0];
  const float* idx_t  = (const float*)d_in[1];
  const float* idx_ir = (const float*)d_in[2];
  const float* Wli = (const float*)d_in[3];
  const float* bli = (const float*)d_in[4];
  const float* Wlt = (const float*)d_in[5];
  const float* blt = (const float*)d_in[6];
  const float* Wlir = (const float*)d_in[7];
  const float* blir = (const float*)d_in[8];
  const float* Wlo = (const float*)d_in[9];
  const float* blo = (const float*)d_in[10];
  const float* Wp  = (const float*)d_in[11];
  const float* bp  = (const float*)d_in[12];
  const float* Wk  = (const float*)d_in[13];
  const float* bk  = (const float*)d_in[14];
  const float* Wpi = (const float*)d_in[15];
  const float* bpi = (const float*)d_in[16];
  const float* Wki = (const float*)d_in[17];
  const float* bki = (const float*)d_in[18];
  const float* Wv  = (const float*)d_in[19];
  const float* bv  = (const float*)d_in[20];

  const i64 SLAB = (i64)NBC * FULL * FULL;   // 6,291,456 floats = 25.2 MB
  float* ws0 = (float*)d_ws;
  float* ws1 = ws0 + SLAB;
  float* ws2 = ws1 + SLAB;
  float* Mbuf = ws2 + SLAB;                  // 192*64*64 floats = 3.1 MB
  float* bufD = (float*)d_out;               // reuse output as scratch

  dim3 blk(256);
  dim3 g88(8, 8, NBC);
  dim3 gproj(1, 8, NBC * 8);

  // x = idx_i + idx_t + idx_ir -> ws0
  add3_kernel<<<2048, blk, 0, stream>>>((const float4*)idx_i, (const float4*)idx_t,
                                        (const float4*)idx_ir, (float4*)ws0, (int)(SLAB / 4));
  // xi = x@Wli + bli -> ws1
  gemm_f32<<<g88, blk, 0, stream>>>(ws0, Wli, bli, ws1, 512, 512, 1, SLAB / NBC * 0 + 262144LL, 1, 0LL, 1);
  // xt = idx_t@Wlt + blt -> ws0
  gemm_f32<<<g88, blk, 0, stream>>>(idx_t, Wlt, blt, ws0, 512, 512, 1, 262144LL, 1, 0LL, 1);
  // xir = idx_ir@Wlir + blir -> ws2
  gemm_f32<<<g88, blk, 0, stream>>>(idx_ir, Wlir, blir, ws2, 512, 512, 1, 262144LL, 1, 0LL, 1);
  // t1 = xi@xt -> bufD
  gemm_f32<<<g88, blk, 0, stream>>>(ws1, ws0, nullptr, bufD, 512, 512, 1, 262144LL, NBC, 262144LL, 1);
  // t2 = t1@xir -> ws1
  gemm_f32<<<g88, blk, 0, stream>>>(bufD, ws2, nullptr, ws1, 512, 512, 1, 262144LL, NBC, 262144LL, 1);
  // xi2 = t2@Wlo + blo -> bufD
  gemm_f32<<<g88, blk, 0, stream>>>(ws1, Wlo, blo, bufD, 512, 512, 1, 262144LL, 1, 0LL, 1);
  // key = xt@Wk + bk -> ws1   (xt in ws0)
  gemm_f32<<<gproj, blk, 0, stream>>>(ws0, Wk, bk, ws1, 64, 512, 8, 262144LL, 8, 32768LL, 8);
  // M = key^T @ Wpi -> Mbuf
  mh_kernel<<<192, blk, 0, stream>>>(ws1, Wpi, Mbuf);
  // key_i = xir@Wki + bki -> ws0   (xir in ws2)
  gemm_f32<<<gproj, blk, 0, stream>>>(ws2, Wki, bki, ws0, 64, 512, 8, 262144LL, 8, 32768LL, 8);
  // pos = xi2@Wp + bp -> ws1  (key dead after M)
  gemm_f32<<<gproj, blk, 0, stream>>>(bufD, Wp, bp, ws1, 64, 512, 8, 262144LL, 8, 32768LL, 8);
  // val = xi2@Wv + bv -> ws2  (xir dead)
  gemm_f32<<<gproj, blk, 0, stream>>>(bufD, Wv, bv, ws2, 64, 512, 8, 262144LL, 8, 32768LL, 8);
  // q2 = 0.125*pos@M + bpi, in place on ws1
  q2_kernel<<<dim3(8, 192), blk, 0, stream>>>(ws1, Mbuf, bpi);
  // out = causal-softmax(0.125*q2@key_i^T) @ val -> d_out
  attn_kernel<<<dim3(8, 192), blk, 0, stream>>>(ws1, ws0, ws2, (float*)d_out);
}

// Round 2
// 630.838 us; speedup vs baseline: 1.9118x; 1.9118x over previous
//
#include <hip/hip_runtime.h>

typedef long long i64;
typedef __attribute__((ext_vector_type(4))) float f32x4;
typedef __attribute__((ext_vector_type(8))) __bf16 bf16x8;

#define FULL 512
#define NBC  24   // B*C = 8*3

__device__ __forceinline__ void gload_lds16(const void* g, void* l) {
  __builtin_amdgcn_global_load_lds(
      (const __attribute__((address_space(1))) void*)g,
      (__attribute__((address_space(3))) void*)l, 16, 0, 0);
}

__device__ __forceinline__ ushort f32_to_bf16_rtn(float x) {
  unsigned u = __float_as_uint(x);
  return (ushort)((u + 0x7FFFu + ((u >> 16) & 1u)) >> 16);
}

// ---------------------------------------------------------------- add3 + split inputs
// x = a+b+c -> (xh,xl); b -> (bh,bl); c -> (ch,cl)
__global__ __launch_bounds__(256) void add3_split(
    const float4* __restrict__ a, const float4* __restrict__ b, const float4* __restrict__ c,
    ushort4* __restrict__ xh, ushort4* __restrict__ xl,
    ushort4* __restrict__ bh, ushort4* __restrict__ bl,
    ushort4* __restrict__ ch, ushort4* __restrict__ cl, int n4) {
  int i = blockIdx.x * 256 + threadIdx.x;
  int stride = gridDim.x * 256;
  for (; i < n4; i += stride) {
    float4 va = a[i], vb = b[i], vc = c[i];
    float xs[4] = {va.x + vb.x + vc.x, va.y + vb.y + vc.y,
                   va.z + vb.z + vc.z, va.w + vb.w + vc.w};
    float bs[4] = {vb.x, vb.y, vb.z, vb.w};
    float cs[4] = {vc.x, vc.y, vc.z, vc.w};
    ushort4 h, l;
    ushort* hp = (ushort*)&h; ushort* lp = (ushort*)&l;
    #pragma unroll
    for (int k = 0; k < 4; ++k) {
      ushort hh = f32_to_bf16_rtn(xs[k]); hp[k] = hh;
      lp[k] = f32_to_bf16_rtn(xs[k] - __uint_as_float((unsigned)hh << 16));
    }
    xh[i] = h; xl[i] = l;
    #pragma unroll
    for (int k = 0; k < 4; ++k) {
      ushort hh = f32_to_bf16_rtn(bs[k]); hp[k] = hh;
      lp[k] = f32_to_bf16_rtn(bs[k] - __uint_as_float((unsigned)hh << 16));
    }
    bh[i] = h; bl[i] = l;
    #pragma unroll
    for (int k = 0; k < 4; ++k) {
      ushort hh = f32_to_bf16_rtn(cs[k]); hp[k] = hh;
      lp[k] = f32_to_bf16_rtn(cs[k] - __uint_as_float((unsigned)hh << 16));
    }
    ch[i] = h; cl[i] = l;
  }
}

// ---------------------------------------------------------------- fused transpose+split for weights
// in fp32 [R][C] (batched) -> outH/outL bf16 [C][R] at row offset per batch
__global__ __launch_bounds__(256) void transposeSplitW(
    const float* __restrict__ in, ushort* __restrict__ outH, ushort* __restrict__ outL,
    int inLD, int outLD, i64 inBatch, i64 outBatch) {
  int b = blockIdx.z;
  const float* I = in + (i64)b * inBatch;
  int r0 = blockIdx.y * 64, c0 = blockIdx.x * 64;
  __shared__ ushort sH[64][68];
  __shared__ ushort sL[64][68];
  int tid = threadIdx.x, tx = tid & 15, ty = tid >> 4;
  #pragma unroll
  for (int it = 0; it < 4; ++it) {
    int r = it * 16 + ty;
    float4 v = *(const float4*)&I[(i64)(r0 + r) * inLD + c0 + tx * 4];
    float vs[4] = {v.x, v.y, v.z, v.w};
    #pragma unroll
    for (int k = 0; k < 4; ++k) {
      ushort hh = f32_to_bf16_rtn(vs[k]);
      sH[tx * 4 + k][r] = hh;
      sL[tx * 4 + k][r] = f32_to_bf16_rtn(vs[k] - __uint_as_float((unsigned)hh << 16));
    }
  }
  __syncthreads();
  #pragma unroll
  for (int it = 0; it < 4; ++it) {
    int c = it * 16 + ty;
    ushort4 hv, lv;
    ushort* hp = (ushort*)&hv; ushort* lp = (ushort*)&lv;
    #pragma unroll
    for (int k = 0; k < 4; ++k) { hp[k] = sH[c][tx * 4 + k]; lp[k] = sL[c][tx * 4 + k]; }
    i64 off = (i64)b * outBatch + (i64)(c0 + c) * outLD + r0 + tx * 4;
    *(ushort4*)&outH[off] = hv;
    *(ushort4*)&outL[off] = lv;
  }
}

// ---------------------------------------------------------------- in-place bf16 transpose (square 512x512, batched)
__global__ __launch_bounds__(256) void transposeIP(ushort* __restrict__ hi, ushort* __restrict__ lo,
                                                   i64 batch) {
  int bi = blockIdx.x, bj = blockIdx.y;
  if (bi > bj) return;
  int z = blockIdx.z;
  ushort* buf = ((z & 1) ? lo : hi) + (i64)(z >> 1) * batch;
  __shared__ ushort tA[64][68];
  __shared__ ushort tB[64][68];
  int tid = threadIdx.x, tx = tid & 15, ty = tid >> 4;
  #pragma unroll
  for (int it = 0; it < 4; ++it) {
    int r = it * 16 + ty;
    ushort4 a = *(const ushort4*)&buf[(i64)(bi * 64 + r) * 512 + bj * 64 + tx * 4];
    ushort* ap = (ushort*)&a;
    #pragma unroll
    for (int k = 0; k < 4; ++k) tA[tx * 4 + k][r] = ap[k];
    if (bi != bj) {
      ushort4 b = *(const ushort4*)&buf[(i64)(bj * 64 + r) * 512 + bi * 64 + tx * 4];
      ushort* bp = (ushort*)&b;
      #pragma unroll
      for (int k = 0; k < 4; ++k) tB[tx * 4 + k][r] = bp[k];
    }
  }
  __syncthreads();
  #pragma unroll
  for (int it = 0; it < 4; ++it) {
    int c = it * 16 + ty;
    ushort4 v; ushort* vp = (ushort*)&v;
    #pragma unroll
    for (int k = 0; k < 4; ++k) vp[k] = tA[c][tx * 4 + k];
    *(ushort4*)&buf[(i64)(bj * 64 + c) * 512 + bi * 64 + tx * 4] = v;
    if (bi != bj) {
      #pragma unroll
      for (int k = 0; k < 4; ++k) vp[k] = tB[c][tx * 4 + k];
      *(ushort4*)&buf[(i64)(bi * 64 + c) * 512 + bj * 64 + tx * 4] = v;
    }
  }
}

// ---------------------------------------------------------------- split-bf16 MFMA GEMM
// C[z](512xN) = A[z](512xK as hi/lo planes) @ B[z%bMod]([N][K] transposed hi/lo planes) + bias
// out: fp32 Cf and/or split planes Chi/Clo
__global__ __launch_bounds__(256, 2) void gemm_split(
    const ushort* __restrict__ Ahi, const ushort* __restrict__ Alo,
    const ushort* __restrict__ Bhi, const ushort* __restrict__ Blo,
    const float* __restrict__ bias,
    float* __restrict__ Cf, ushort* __restrict__ Chi, ushort* __restrict__ Clo,
    int K, int N, i64 aStride, int bMod, i64 bStride, i64 cStride) {
  int z = blockIdx.z;
  int m0 = blockIdx.y * 128, n0 = blockIdx.x * 128;
  const ushort* Ah = Ahi + (i64)z * aStride + (i64)m0 * K;
  const ushort* Al = Alo + (i64)z * aStride + (i64)m0 * K;
  const ushort* Bh = Bhi + (i64)(z % bMod) * bStride + (i64)n0 * K;
  const ushort* Bl = Blo + (i64)(z % bMod) * bStride + (i64)n0 * K;

  __shared__ ushort lds[4 * 128 * 64];   // planes: Ahi, Alo, Bhi, Blo (16KB each)

  int tid = threadIdx.x;
  int lane = tid & 63, wid = tid >> 6;
  int wr = wid >> 1, wc = wid & 1;

  f32x4 acc[4][4] = {};

  for (int k0 = 0; k0 < K; k0 += 64) {
    __syncthreads();
    #pragma unroll
    for (int p = 0; p < 4; ++p) {
      const ushort* gb = (p == 0) ? Ah : (p == 1) ? Al : (p == 2) ? Bh : Bl;
      #pragma unroll
      for (int it = 0; it < 4; ++it) {
        int s = it * 4096 + tid * 16;
        int row = s >> 7;
        int cb = (s & 127) ^ ((row & 7) << 4);          // pre-swizzled source
        const char* g = (const char*)gb + (i64)row * (K * 2) + k0 * 2 + cb;
        char* l = (char*)lds + p * 16384 + it * 4096 + wid * 1024;
        gload_lds16(g, l);
      }
    }
    __syncthreads();  // drains vmcnt(0): LDS tiles ready
    #pragma unroll
    for (int ks = 0; ks < 2; ++ks) {
      bf16x8 aH[4], aL[4], bH[4], bL[4];
      #pragma unroll
      for (int i = 0; i < 4; ++i) {
        int row = wr * 64 + i * 16 + (lane & 15);
        int cb = (ks * 64 + (lane >> 4) * 16) ^ ((row & 7) << 4);
        aH[i] = *(const bf16x8*)((const char*)lds + 0 * 16384 + row * 128 + cb);
        aL[i] = *(const bf16x8*)((const char*)lds + 1 * 16384 + row * 128 + cb);
      }
      #pragma unroll
      for (int j = 0; j < 4; ++j) {
        int row = wc * 64 + j * 16 + (lane & 15);
        int cb = (ks * 64 + (lane >> 4) * 16) ^ ((row & 7) << 4);
        bH[j] = *(const bf16x8*)((const char*)lds + 2 * 16384 + row * 128 + cb);
        bL[j] = *(const bf16x8*)((const char*)lds + 3 * 16384 + row * 128 + cb);
      }
      #pragma unroll
      for (int i = 0; i < 4; ++i)
        #pragma unroll
        for (int j = 0; j < 4; ++j) {
          acc[i][j] = __builtin_amdgcn_mfma_f32_16x16x32_bf16(aH[i], bH[j], acc[i][j], 0, 0, 0);
          acc[i][j] = __builtin_amdgcn_mfma_f32_16x16x32_bf16(aH[i], bL[j], acc[i][j], 0, 0, 0);
          acc[i][j] = __builtin_amdgcn_mfma_f32_16x16x32_bf16(aL[i], bH[j], acc[i][j], 0, 0, 0);
        }
    }
  }

  // epilogue: C/D layout col = lane&15, row = (lane>>4)*4 + q
  int colBase = n0 + wc * 64 + (lane & 15);
  int rowBase = m0 + wr * 64 + (lane >> 4) * 4;
  #pragma unroll
  for (int j = 0; j < 4; ++j) {
    int col = colBase + j * 16;
    float bv = bias ? bias[col] : 0.f;
    #pragma unroll
    for (int i = 0; i < 4; ++i) {
      #pragma unroll
      for (int q = 0; q < 4; ++q) {
        int row = rowBase + i * 16 + q;
        i64 idx = (i64)z * cStride + (i64)row * N + col;
        float v = acc[i][j][q] + bv;
        if (Cf) Cf[idx] = v;
        if (Chi) {
          ushort hh = f32_to_bf16_rtn(v);
          Chi[idx] = hh;
          Clo[idx] = f32_to_bf16_rtn(v - __uint_as_float((unsigned)hh << 16));
        }
      }
    }
  }
}

// ---------------------------------------------------------------- M = key[:,hblk]^T @ Wpi[h]  (fp32)
// key: [bc][512][512] (col block h*64), Wpi: [8][512][64]
__global__ __launch_bounds__(256) void mh_kernel(const float* __restrict__ key,
                                                 const float* __restrict__ Wpi,
                                                 float* __restrict__ M) {
  int z = blockIdx.x, bc = z >> 3, h = z & 7;
  const float* Kb = key + (i64)bc * FULL * FULL + h * 64;
  const float* Wb = Wpi + (i64)h * FULL * 64;
  float* Mb = M + (i64)z * 64 * 64;

  __shared__ float sK[64][68];
  __shared__ float sW[64][68];

  int tid = threadIdx.x, tx = tid & 15, ty = tid >> 4;
  float acc[4][4] = {};

  for (int s0 = 0; s0 < FULL; s0 += 64) {
    __syncthreads();
    #pragma unroll
    for (int it = 0; it < 4; ++it) {
      int idx = tid + it * 256;
      int r = idx >> 4, c4 = idx & 15;
      *(float4*)&sK[r][c4 * 4] = *(const float4*)&Kb[(i64)(s0 + r) * FULL + c4 * 4];
      *(float4*)&sW[r][c4 * 4] = *(const float4*)&Wb[(i64)(s0 + r) * 64 + c4 * 4];
    }
    __syncthreads();
    for (int s = 0; s < 64; ++s) {
      float4 a4 = *(const float4*)&sK[s][ty * 4];
      float4 b4 = *(const float4*)&sW[s][tx * 4];
      float av[4] = {a4.x, a4.y, a4.z, a4.w};
      float bv[4] = {b4.x, b4.y, b4.z, b4.w};
      #pragma unroll
      for (int i = 0; i < 4; ++i)
        #pragma unroll
        for (int j = 0; j < 4; ++j)
          acc[i][j] += av[i] * bv[j];
    }
  }
  #pragma unroll
  for (int i = 0; i < 4; ++i)
    #pragma unroll
    for (int j = 0; j < 4; ++j)
      Mb[(ty * 4 + i) * 64 + tx * 4 + j] = acc[i][j];
}

// ---------------------------------------------------------------- q2 = 0.125*pos[:,hblk]@M + bpi (in place)
__global__ __launch_bounds__(256) void q2_kernel(float* __restrict__ posq2,
                                                 const float* __restrict__ M,
                                                 const float* __restrict__ bpi) {
  int z = blockIdx.y, bc = z >> 3, h = z & 7;
  int t0 = blockIdx.x * 64;
  float* Pb = posq2 + ((i64)bc * FULL + t0) * FULL + h * 64;
  const float* Mb = M + (i64)z * 4096;

  __shared__ float sP[64][68];
  __shared__ float sM[64][68];

  int tid = threadIdx.x, tx = tid & 15, ty = tid >> 4;
  #pragma unroll
  for (int it = 0; it < 4; ++it) {
    int idx = tid + it * 256;
    int r = idx >> 4, c4 = idx & 15;
    *(float4*)&sP[r][c4 * 4] = *(const float4*)&Pb[(i64)r * FULL + c4 * 4];
    *(float4*)&sM[r][c4 * 4] = *(const float4*)&Mb[(i64)r * 64 + c4 * 4];
  }
  __syncthreads();

  float acc[4][4] = {};
  for (int e = 0; e < 64; ++e) {
    float av[4];
    #pragma unroll
    for (int i = 0; i < 4; ++i) av[i] = sP[ty * 4 + i][e];
    float4 b4 = *(const float4*)&sM[e][tx * 4];
    float bv[4] = {b4.x, b4.y, b4.z, b4.w};
    #pragma unroll
    for (int i = 0; i < 4; ++i)
      #pragma unroll
      for (int j = 0; j < 4; ++j)
        acc[i][j] += av[i] * bv[j];
  }
  __syncthreads();
  #pragma unroll
  for (int i = 0; i < 4; ++i) {
    float4 v;
    float* vp = (float*)&v;
    #pragma unroll
    for (int j = 0; j < 4; ++j)
      vp[j] = 0.125f * acc[i][j] + bpi[h * 64 + tx * 4 + j];
    *(float4*)&Pb[(i64)(ty * 4 + i) * FULL + tx * 4] = v;
  }
}

// ---------------------------------------------------------------- flash attention (causal, fp32)
// Q,K,V: [bc][512][512] with head col-block; out: [bc][512][512]
__global__ __launch_bounds__(256) void attn_kernel(const float* __restrict__ Q,
                                                   const float* __restrict__ K,
                                                   const float* __restrict__ V,
                                                   float* __restrict__ out) {
  int z = blockIdx.y, qt = blockIdx.x;
  int bc = z >> 3, h = z & 7;
  const float* Qb = Q + ((i64)bc * FULL + qt * 64) * FULL + h * 64;
  const float* Kb = K + (i64)bc * FULL * FULL + h * 64;
  const float* Vb = V + (i64)bc * FULL * FULL + h * 64;

  __shared__ float sQ[64][68];
  __shared__ float sK[64][68];
  __shared__ float sV[64][68];
  __shared__ float sP[64][68];

  int tid = threadIdx.x, tx = tid & 15, ty = tid >> 4;

  #pragma unroll
  for (int it = 0; it < 4; ++it) {
    int idx = tid + it * 256;
    int r = idx >> 4, c4 = idx & 15;
    *(float4*)&sQ[r][c4 * 4] = *(const float4*)&Qb[(i64)r * FULL + c4 * 4];
  }

  float m_i[4], l_i[4], acc[4][4] = {};
  #pragma unroll
  for (int i = 0; i < 4; ++i) { m_i[i] = -3e38f; l_i[i] = 0.f; }

  for (int st = 0; st <= qt; ++st) {
    __syncthreads();
    #pragma unroll
    for (int it = 0; it < 4; ++it) {
      int idx = tid + it * 256;
      int r = idx >> 4, c4 = idx & 15;
      *(float4*)&sK[r][c4 * 4] = *(const float4*)&Kb[((i64)st * 64 + r) * FULL + c4 * 4];
      *(float4*)&sV[r][c4 * 4] = *(const float4*)&Vb[((i64)st * 64 + r) * FULL + c4 * 4];
    }
    __syncthreads();

    float s[4][4] = {};
    for (int d4 = 0; d4 < 16; ++d4) {
      float4 q4[4], k4[4];
      #pragma unroll
      for (int i = 0; i < 4; ++i) q4[i] = *(const float4*)&sQ[ty * 4 + i][d4 * 4];
      #pragma unroll
      for (int j = 0; j < 4; ++j) k4[j] = *(const float4*)&sK[tx * 4 + j][d4 * 4];
      #pragma unroll
      for (int i = 0; i < 4; ++i) {
        float qa[4] = {q4[i].x, q4[i].y, q4[i].z, q4[i].w};
        #pragma unroll
        for (int j = 0; j < 4; ++j) {
          float ka[4] = {k4[j].x, k4[j].y, k4[j].z, k4[j].w};
          s[i][j] += qa[0]*ka[0] + qa[1]*ka[1] + qa[2]*ka[2] + qa[3]*ka[3];
        }
      }
    }
    #pragma unroll
    for (int i = 0; i < 4; ++i)
      #pragma unroll
      for (int j = 0; j < 4; ++j)
        s[i][j] *= 0.125f;

    if (st == qt) {
      #pragma unroll
      for (int i = 0; i < 4; ++i)
        #pragma unroll
        for (int j = 0; j < 4; ++j)
          if (tx * 4 + j > ty * 4 + i) s[i][j] = -3e38f;
    }

    float rm[4];
    #pragma unroll
    for (int i = 0; i < 4; ++i)
      rm[i] = fmaxf(fmaxf(s[i][0], s[i][1]), fmaxf(s[i][2], s[i][3]));
    #pragma unroll
    for (int off = 8; off >= 1; off >>= 1)
      #pragma unroll
      for (int i = 0; i < 4; ++i)
        rm[i] = fmaxf(rm[i], __shfl_xor(rm[i], off, 64));

    float alpha[4], p[4][4], rs[4];
    #pragma unroll
    for (int i = 0; i < 4; ++i) {
      float mn = fmaxf(m_i[i], rm[i]);
      alpha[i] = __expf(m_i[i] - mn);
      m_i[i] = mn;
      rs[i] = 0.f;
      #pragma unroll
      for (int j = 0; j < 4; ++j) {
        p[i][j] = __expf(s[i][j] - mn);
        rs[i] += p[i][j];
      }
    }
    #pragma unroll
    for (int off = 8; off >= 1; off >>= 1)
      #pragma unroll
      for (int i = 0; i < 4; ++i)
        rs[i] += __shfl_xor(rs[i], off, 64);
    #pragma unroll
    for (int i = 0; i < 4; ++i) {
      l_i[i] = l_i[i] * alpha[i] + rs[i];
      #pragma unroll
      for (int j = 0; j < 4; ++j) acc[i][j] *= alpha[i];
    }

    #pragma unroll
    for (int i = 0; i < 4; ++i)
      #pragma unroll
      for (int j = 0; j < 4; ++j)
        sP[ty * 4 + i][tx * 4 + j] = p[i][j];
    __syncthreads();

    for (int s4 = 0; s4 < 16; ++s4) {
      float4 p4[4], v4[4];
      #pragma unroll
      for (int i = 0; i < 4; ++i) p4[i] = *(const float4*)&sP[ty * 4 + i][s4 * 4];
      #pragma unroll
      for (int k = 0; k < 4; ++k) v4[k] = *(const float4*)&sV[s4 * 4 + k][tx * 4];
      #pragma unroll
      for (int i = 0; i < 4; ++i) {
        float pa[4] = {p4[i].x, p4[i].y, p4[i].z, p4[i].w};
        #pragma unroll
        for (int k = 0; k < 4; ++k) {
          float va[4] = {v4[k].x, v4[k].y, v4[k].z, v4[k].w};
          #pragma unroll
          for (int j = 0; j < 4; ++j)
            acc[i][j] += pa[k] * va[j];
        }
      }
    }
  }

  #pragma unroll
  for (int i = 0; i < 4; ++i) {
    float inv = 1.f / l_i[i];
    int t = qt * 64 + ty * 4 + i;
    float4 v;
    float* vp = (float*)&v;
    #pragma unroll
    for (int j = 0; j < 4; ++j) vp[j] = acc[i][j] * inv;
    *(float4*)&out[((i64)bc * FULL + t) * FULL + h * 64 + tx * 4] = v;
  }
}

// ---------------------------------------------------------------- launch
extern "C" void kernel_launch(void* const* d_in, const int* in_sizes, int n_in,
                              void* d_out, int out_size, void* d_ws, size_t ws_size,
                              hipStream_t stream) {
  const float* idx_i  = (const float*)d_in[0];
  const float* idx_t  = (const float*)d_in[1];
  const float* idx_ir = (const float*)d_in[2];
  const float* Wli = (const float*)d_in[3];
  const float* bli = (const float*)d_in[4];
  const float* Wlt = (const float*)d_in[5];
  const float* blt = (const float*)d_in[6];
  const float* Wlir = (const float*)d_in[7];
  const float* blir = (const float*)d_in[8];
  const float* Wlo = (const float*)d_in[9];
  const float* blo = (const float*)d_in[10];
  const float* Wp  = (const float*)d_in[11];
  const float* bp  = (const float*)d_in[12];
  const float* Wk  = (const float*)d_in[13];
  const float* bk  = (const float*)d_in[14];
  const float* Wpi = (const float*)d_in[15];
  const float* bpi = (const float*)d_in[16];
  const float* Wki = (const float*)d_in[17];
  const float* bki = (const float*)d_in[18];
  const float* Wv  = (const float*)d_in[19];
  const float* bv  = (const float*)d_in[20];

  const i64 PL = (i64)NBC * FULL * FULL;      // 6,291,456 (plane slab, ushorts)
  const i64 WPL = (i64)FULL * FULL;           // 262,144  (weight plane, ushorts)
  ushort* U = (ushort*)d_ws;
  ushort* slab[8];
  for (int s = 0; s < 8; ++s) slab[s] = U + (i64)s * PL;
  ushort* wreg = U + 8 * PL;
  // weight-T planes: w = 0:li 1:lt 2:lir 3:lo 4:k 5:ki 6:p 7:v
  ushort* WT[8][2];
  for (int w = 0; w < 8; ++w)
    for (int p = 0; p < 2; ++p) WT[w][p] = wreg + (i64)(w * 2 + p) * WPL;
  float* Mbuf = (float*)(wreg + 16 * WPL);    // 192*64*64 fp32

  dim3 blk(256);
  dim3 gGemm(4, 4, NBC);
  const i64 AS = (i64)FULL * FULL;  // 262144: per-z activation stride (elems)

  // ---- weight prep: fused transpose+split ----
  const float* Wbig[4] = {Wli, Wlt, Wlir, Wlo};
  for (int w = 0; w < 4; ++w)
    transposeSplitW<<<dim3(8, 8, 1), blk, 0, stream>>>(Wbig[w], WT[w][0], WT[w][1],
                                                       512, 512, 0, 0);
  const float* Whead[4] = {Wk, Wki, Wp, Wv};
  for (int w = 0; w < 4; ++w)
    transposeSplitW<<<dim3(1, 8, 8), blk, 0, stream>>>(Whead[w], WT[4 + w][0], WT[4 + w][1],
                                                       64, 512, 512 * 64, 64 * 512);

  // ---- input splits: x->(0,1), idx_t->(2,3), idx_ir->(4,5) ----
  add3_split<<<2048, blk, 0, stream>>>((const float4*)idx_i, (const float4*)idx_t,
                                       (const float4*)idx_ir,
                                       (ushort4*)slab[0], (ushort4*)slab[1],
                                       (ushort4*)slab[2], (ushort4*)slab[3],
                                       (ushort4*)slab[4], (ushort4*)slab[5], (int)(PL / 4));

  // xi = x@Wli + bli -> planes (6,7); x dies
  gemm_split<<<gGemm, blk, 0, stream>>>(slab[0], slab[1], WT[0][0], WT[0][1], bli,
                                        nullptr, slab[6], slab[7], 512, 512, AS, 1, 0, AS);
  // xt = idx_t@Wlt + blt -> planes (0,1); idx_t split dies
  gemm_split<<<gGemm, blk, 0, stream>>>(slab[2], slab[3], WT[1][0], WT[1][1], blt,
                                        nullptr, slab[0], slab[1], 512, 512, AS, 1, 0, AS);
  // key = xt@Wk_flat + bk -> fp32 in d_out
  gemm_split<<<gGemm, blk, 0, stream>>>(slab[0], slab[1], WT[4][0], WT[4][1], bk,
                                        (float*)d_out, nullptr, nullptr, 512, 512, AS, 1, 0, AS);
  // M = key[:,hblk]^T @ Wpi[h]
  mh_kernel<<<192, blk, 0, stream>>>((const float*)d_out, Wpi, Mbuf);
  // xt -> xtT in place (0,1)
  transposeIP<<<dim3(8, 8, 48), blk, 0, stream>>>(slab[0], slab[1], AS);
  // xir = idx_ir@Wlir + blir -> planes (2,3); idx_ir split dies
  gemm_split<<<gGemm, blk, 0, stream>>>(slab[4], slab[5], WT[2][0], WT[2][1], blir,
                                        nullptr, slab[2], slab[3], 512, 512, AS, 1, 0, AS);
  // t1 = xi@xtT -> planes (4,5); xi alive in (6,7)
  gemm_split<<<gGemm, blk, 0, stream>>>(slab[6], slab[7], slab[0], slab[1], nullptr,
                                        nullptr, slab[4], slab[5], 512, 512, AS, NBC, AS, AS);
  // key_i = xir@Wki + bki -> fp32 at slabs (6,7); xi dead
  float* keyi = (float*)slab[6];
  gemm_split<<<gGemm, blk, 0, stream>>>(slab[2], slab[3], WT[5][0], WT[5][1], bki,
                                        keyi, nullptr, nullptr, 512, 512, AS, 1, 0, AS);
  // xir -> xirT in place (2,3)
  transposeIP<<<dim3(8, 8, 48), blk, 0, stream>>>(slab[2], slab[3], AS);
  // t2 = t1@xirT -> planes (0,1); xtT dead
  gemm_split<<<gGemm, blk, 0, stream>>>(slab[4], slab[5], slab[2], slab[3], nullptr,
                                        nullptr, slab[0], slab[1], 512, 512, AS, NBC, AS, AS);
  // xi2 = t2@Wlo + blo -> planes (2,3); xirT dead
  gemm_split<<<gGemm, blk, 0, stream>>>(slab[0], slab[1], WT[3][0], WT[3][1], blo,
                                        nullptr, slab[2], slab[3], 512, 512, AS, 1, 0, AS);
  // pos = xi2@Wp + bp -> fp32 at slabs (4,5); t1 dead
  float* pos = (float*)slab[4];
  gemm_split<<<gGemm, blk, 0, stream>>>(slab[2], slab[3], WT[6][0], WT[6][1], bp,
                                        pos, nullptr, nullptr, 512, 512, AS, 1, 0, AS);
  // val = xi2@Wv + bv -> fp32 at slabs (0,1); t2 dead
  float* val = (float*)slab[0];
  gemm_split<<<gGemm, blk, 0, stream>>>(slab[2], slab[3], WT[7][0], WT[7][1], bv,
                                        val, nullptr, nullptr, 512, 512, AS, 1, 0, AS);
  // q2 = 0.125*pos@M + bpi (in place on pos)
  q2_kernel<<<dim3(8, 192), blk, 0, stream>>>(pos, Mbuf, bpi);
  // out = causal-softmax(0.125*q2@key_i^T) @ val
  attn_kernel<<<dim3(8, 192), blk, 0, stream>>>(pos, keyi, val, (float*)d_out);
}

// Round 3
// 525.053 us; speedup vs baseline: 2.2970x; 1.2015x over previous
//
#include <hip/hip_runtime.h>

typedef long long i64;
typedef __attribute__((ext_vector_type(4))) float f32x4;
typedef __attribute__((ext_vector_type(8))) __bf16 bf16x8;

#define FULL 512
#define NBC  24   // B*C = 8*3

__device__ __forceinline__ void gload_lds16(const void* g, void* l) {
  __builtin_amdgcn_global_load_lds(
      (const __attribute__((address_space(1))) void*)g,
      (__attribute__((address_space(3))) void*)l, 16, 0, 0);
}

__device__ __forceinline__ ushort f32_to_bf16_rtn(float x) {
  unsigned u = __float_as_uint(x);
  return (ushort)((u + 0x7FFFu + ((u >> 16) & 1u)) >> 16);
}

// ---------------------------------------------------------------- add3 + split inputs
__global__ __launch_bounds__(256) void add3_split(
    const float4* __restrict__ a, const float4* __restrict__ b, const float4* __restrict__ c,
    ushort4* __restrict__ xh, ushort4* __restrict__ xl,
    ushort4* __restrict__ bh, ushort4* __restrict__ bl,
    ushort4* __restrict__ ch, ushort4* __restrict__ cl, int n4) {
  int i = blockIdx.x * 256 + threadIdx.x;
  int stride = gridDim.x * 256;
  for (; i < n4; i += stride) {
    float4 va = a[i], vb = b[i], vc = c[i];
    float xs[4] = {va.x + vb.x + vc.x, va.y + vb.y + vc.y,
                   va.z + vb.z + vc.z, va.w + vb.w + vc.w};
    float bs[4] = {vb.x, vb.y, vb.z, vb.w};
    float cs[4] = {vc.x, vc.y, vc.z, vc.w};
    ushort4 h, l;
    ushort* hp = (ushort*)&h; ushort* lp = (ushort*)&l;
    #pragma unroll
    for (int k = 0; k < 4; ++k) {
      ushort hh = f32_to_bf16_rtn(xs[k]); hp[k] = hh;
      lp[k] = f32_to_bf16_rtn(xs[k] - __uint_as_float((unsigned)hh << 16));
    }
    xh[i] = h; xl[i] = l;
    #pragma unroll
    for (int k = 0; k < 4; ++k) {
      ushort hh = f32_to_bf16_rtn(bs[k]); hp[k] = hh;
      lp[k] = f32_to_bf16_rtn(bs[k] - __uint_as_float((unsigned)hh << 16));
    }
    bh[i] = h; bl[i] = l;
    #pragma unroll
    for (int k = 0; k < 4; ++k) {
      ushort hh = f32_to_bf16_rtn(cs[k]); hp[k] = hh;
      lp[k] = f32_to_bf16_rtn(cs[k] - __uint_as_float((unsigned)hh << 16));
    }
    ch[i] = h; cl[i] = l;
  }
}

// ---------------------------------------------------------------- fused transpose+split for weights
__global__ __launch_bounds__(256) void transposeSplitW(
    const float* __restrict__ in, ushort* __restrict__ outH, ushort* __restrict__ outL,
    int inLD, int outLD, i64 inBatch, i64 outBatch) {
  int b = blockIdx.z;
  const float* I = in + (i64)b * inBatch;
  int r0 = blockIdx.y * 64, c0 = blockIdx.x * 64;
  __shared__ ushort sH[64][68];
  __shared__ ushort sL[64][68];
  int tid = threadIdx.x, tx = tid & 15, ty = tid >> 4;
  #pragma unroll
  for (int it = 0; it < 4; ++it) {
    int r = it * 16 + ty;
    float4 v = *(const float4*)&I[(i64)(r0 + r) * inLD + c0 + tx * 4];
    float vs[4] = {v.x, v.y, v.z, v.w};
    #pragma unroll
    for (int k = 0; k < 4; ++k) {
      ushort hh = f32_to_bf16_rtn(vs[k]);
      sH[tx * 4 + k][r] = hh;
      sL[tx * 4 + k][r] = f32_to_bf16_rtn(vs[k] - __uint_as_float((unsigned)hh << 16));
    }
  }
  __syncthreads();
  #pragma unroll
  for (int it = 0; it < 4; ++it) {
    int c = it * 16 + ty;
    ushort4 hv, lv;
    ushort* hp = (ushort*)&hv; ushort* lp = (ushort*)&lv;
    #pragma unroll
    for (int k = 0; k < 4; ++k) { hp[k] = sH[c][tx * 4 + k]; lp[k] = sL[c][tx * 4 + k]; }
    i64 off = (i64)b * outBatch + (i64)(c0 + c) * outLD + r0 + tx * 4;
    *(ushort4*)&outH[off] = hv;
    *(ushort4*)&outL[off] = lv;
  }
}

// ---------------------------------------------------------------- in-place bf16 transpose (512x512, batched)
__global__ __launch_bounds__(256) void transposeIP(ushort* __restrict__ hi, ushort* __restrict__ lo,
                                                   i64 batch) {
  int bi = blockIdx.x, bj = blockIdx.y;
  if (bi > bj) return;
  int z = blockIdx.z;
  ushort* buf = ((z & 1) ? lo : hi) + (i64)(z >> 1) * batch;
  __shared__ ushort tA[64][68];
  __shared__ ushort tB[64][68];
  int tid = threadIdx.x, tx = tid & 15, ty = tid >> 4;
  #pragma unroll
  for (int it = 0; it < 4; ++it) {
    int r = it * 16 + ty;
    ushort4 a = *(const ushort4*)&buf[(i64)(bi * 64 + r) * 512 + bj * 64 + tx * 4];
    ushort* ap = (ushort*)&a;
    #pragma unroll
    for (int k = 0; k < 4; ++k) tA[tx * 4 + k][r] = ap[k];
    if (bi != bj) {
      ushort4 b = *(const ushort4*)&buf[(i64)(bj * 64 + r) * 512 + bi * 64 + tx * 4];
      ushort* bp = (ushort*)&b;
      #pragma unroll
      for (int k = 0; k < 4; ++k) tB[tx * 4 + k][r] = bp[k];
    }
  }
  __syncthreads();
  #pragma unroll
  for (int it = 0; it < 4; ++it) {
    int c = it * 16 + ty;
    ushort4 v; ushort* vp = (ushort*)&v;
    #pragma unroll
    for (int k = 0; k < 4; ++k) vp[k] = tA[c][tx * 4 + k];
    *(ushort4*)&buf[(i64)(bj * 64 + c) * 512 + bi * 64 + tx * 4] = v;
    if (bi != bj) {
      #pragma unroll
      for (int k = 0; k < 4; ++k) vp[k] = tB[c][tx * 4 + k];
      *(ushort4*)&buf[(i64)(bi * 64 + c) * 512 + bj * 64 + tx * 4] = v;
    }
  }
}

// ---------------------------------------------------------------- split-bf16 MFMA GEMM
// C[z](512xN) = A[z] @ B[z%bMod]^T (+bias); out fp32 and/or split planes (optionally transposed)
__global__ __launch_bounds__(256, 2) void gemm_split(
    const ushort* __restrict__ Ahi, const ushort* __restrict__ Alo,
    const ushort* __restrict__ Bhi, const ushort* __restrict__ Blo,
    const float* __restrict__ bias,
    float* __restrict__ Cf, ushort* __restrict__ Chi, ushort* __restrict__ Clo,
    int K, int N, i64 aStride, int bMod, i64 bStride, i64 cStride, int transC) {
  int z = blockIdx.z;
  int m0 = blockIdx.y * 128, n0 = blockIdx.x * 128;
  const ushort* Ah = Ahi + (i64)z * aStride + (i64)m0 * K;
  const ushort* Al = Alo + (i64)z * aStride + (i64)m0 * K;
  const ushort* Bh = Bhi + (i64)(z % bMod) * bStride + (i64)n0 * K;
  const ushort* Bl = Blo + (i64)(z % bMod) * bStride + (i64)n0 * K;

  __shared__ ushort lds[4 * 128 * 64];

  int tid = threadIdx.x;
  int lane = tid & 63, wid = tid >> 6;
  int wr = wid >> 1, wc = wid & 1;

  f32x4 acc[4][4] = {};

  for (int k0 = 0; k0 < K; k0 += 64) {
    __syncthreads();
    #pragma unroll
    for (int p = 0; p < 4; ++p) {
      const ushort* gb = (p == 0) ? Ah : (p == 1) ? Al : (p == 2) ? Bh : Bl;
      #pragma unroll
      for (int it = 0; it < 4; ++it) {
        int s = it * 4096 + tid * 16;
        int row = s >> 7;
        int cb = (s & 127) ^ ((row & 7) << 4);
        const char* g = (const char*)gb + (i64)row * (K * 2) + k0 * 2 + cb;
        char* l = (char*)lds + p * 16384 + it * 4096 + wid * 1024;
        gload_lds16(g, l);
      }
    }
    __syncthreads();
    #pragma unroll
    for (int ks = 0; ks < 2; ++ks) {
      bf16x8 aH[4], aL[4], bH[4], bL[4];
      #pragma unroll
      for (int i = 0; i < 4; ++i) {
        int row = wr * 64 + i * 16 + (lane & 15);
        int cb = (ks * 64 + (lane >> 4) * 16) ^ ((row & 7) << 4);
        aH[i] = *(const bf16x8*)((const char*)lds + 0 * 16384 + row * 128 + cb);
        aL[i] = *(const bf16x8*)((const char*)lds + 1 * 16384 + row * 128 + cb);
      }
      #pragma unroll
      for (int j = 0; j < 4; ++j) {
        int row = wc * 64 + j * 16 + (lane & 15);
        int cb = (ks * 64 + (lane >> 4) * 16) ^ ((row & 7) << 4);
        bH[j] = *(const bf16x8*)((const char*)lds + 2 * 16384 + row * 128 + cb);
        bL[j] = *(const bf16x8*)((const char*)lds + 3 * 16384 + row * 128 + cb);
      }
      #pragma unroll
      for (int i = 0; i < 4; ++i)
        #pragma unroll
        for (int j = 0; j < 4; ++j) {
          acc[i][j] = __builtin_amdgcn_mfma_f32_16x16x32_bf16(aH[i], bH[j], acc[i][j], 0, 0, 0);
          acc[i][j] = __builtin_amdgcn_mfma_f32_16x16x32_bf16(aH[i], bL[j], acc[i][j], 0, 0, 0);
          acc[i][j] = __builtin_amdgcn_mfma_f32_16x16x32_bf16(aL[i], bH[j], acc[i][j], 0, 0, 0);
        }
    }
  }

  int colBase = n0 + wc * 64 + (lane & 15);
  int rowBase = m0 + wr * 64 + (lane >> 4) * 4;
  #pragma unroll
  for (int j = 0; j < 4; ++j) {
    int col = colBase + j * 16;
    float bv = bias ? bias[col] : 0.f;
    #pragma unroll
    for (int i = 0; i < 4; ++i) {
      #pragma unroll
      for (int q = 0; q < 4; ++q) {
        int row = rowBase + i * 16 + q;
        i64 idx = (i64)z * cStride +
                  (transC ? ((i64)col * N + row) : ((i64)row * N + col));
        float v = acc[i][j][q] + bv;
        if (Cf) Cf[idx] = v;
        if (Chi) {
          ushort hh = f32_to_bf16_rtn(v);
          Chi[idx] = hh;
          Clo[idx] = f32_to_bf16_rtn(v - __uint_as_float((unsigned)hh << 16));
        }
      }
    }
  }
}

// ---------------------------------------------------------------- M = key[:,hblk]^T @ Wpi[h]  (fp32)
__global__ __launch_bounds__(256) void mh_kernel(const float* __restrict__ key,
                                                 const float* __restrict__ Wpi,
                                                 float* __restrict__ M) {
  int z = blockIdx.x, bc = z >> 3, h = z & 7;
  const float* Kb = key + (i64)bc * FULL * FULL + h * 64;
  const float* Wb = Wpi + (i64)h * FULL * 64;
  float* Mb = M + (i64)z * 64 * 64;

  __shared__ float sK[64][68];
  __shared__ float sW[64][68];

  int tid = threadIdx.x, tx = tid & 15, ty = tid >> 4;
  float acc[4][4] = {};

  for (int s0 = 0; s0 < FULL; s0 += 64) {
    __syncthreads();
    #pragma unroll
    for (int it = 0; it < 4; ++it) {
      int idx = tid + it * 256;
      int r = idx >> 4, c4 = idx & 15;
      *(float4*)&sK[r][c4 * 4] = *(const float4*)&Kb[(i64)(s0 + r) * FULL + c4 * 4];
      *(float4*)&sW[r][c4 * 4] = *(const float4*)&Wb[(i64)(s0 + r) * 64 + c4 * 4];
    }
    __syncthreads();
    for (int s = 0; s < 64; ++s) {
      float4 a4 = *(const float4*)&sK[s][ty * 4];
      float4 b4 = *(const float4*)&sW[s][tx * 4];
      float av[4] = {a4.x, a4.y, a4.z, a4.w};
      float bv[4] = {b4.x, b4.y, b4.z, b4.w};
      #pragma unroll
      for (int i = 0; i < 4; ++i)
        #pragma unroll
        for (int j = 0; j < 4; ++j)
          acc[i][j] += av[i] * bv[j];
    }
  }
  #pragma unroll
  for (int i = 0; i < 4; ++i)
    #pragma unroll
    for (int j = 0; j < 4; ++j)
      Mb[(ty * 4 + i) * 64 + tx * 4 + j] = acc[i][j];
}

// ---------------------------------------------------------------- q2 = 0.125*pos[:,hblk]@M + bpi -> split planes
__global__ __launch_bounds__(256) void q2_split_kernel(const float* __restrict__ pos,
                                                       const float* __restrict__ M,
                                                       const float* __restrict__ bpi,
                                                       ushort* __restrict__ Qh,
                                                       ushort* __restrict__ Ql) {
  int z = blockIdx.y, bc = z >> 3, h = z & 7;
  int t0 = blockIdx.x * 64;
  const float* Pb = pos + ((i64)bc * FULL + t0) * FULL + h * 64;
  const float* Mb = M + (i64)z * 4096;

  __shared__ float sP[64][68];
  __shared__ float sM[64][68];

  int tid = threadIdx.x, tx = tid & 15, ty = tid >> 4;
  #pragma unroll
  for (int it = 0; it < 4; ++it) {
    int idx = tid + it * 256;
    int r = idx >> 4, c4 = idx & 15;
    *(float4*)&sP[r][c4 * 4] = *(const float4*)&Pb[(i64)r * FULL + c4 * 4];
    *(float4*)&sM[r][c4 * 4] = *(const float4*)&Mb[(i64)r * 64 + c4 * 4];
  }
  __syncthreads();

  float acc[4][4] = {};
  for (int e = 0; e < 64; ++e) {
    float av[4];
    #pragma unroll
    for (int i = 0; i < 4; ++i) av[i] = sP[ty * 4 + i][e];
    float4 b4 = *(const float4*)&sM[e][tx * 4];
    float bv[4] = {b4.x, b4.y, b4.z, b4.w};
    #pragma unroll
    for (int i = 0; i < 4; ++i)
      #pragma unroll
      for (int j = 0; j < 4; ++j)
        acc[i][j] += av[i] * bv[j];
  }
  i64 base = ((i64)bc * FULL + t0) * FULL + h * 64;
  #pragma unroll
  for (int i = 0; i < 4; ++i) {
    #pragma unroll
    for (int j = 0; j < 4; ++j) {
      float v = 0.125f * acc[i][j] + bpi[h * 64 + tx * 4 + j];
      i64 idx = base + (i64)(ty * 4 + i) * FULL + tx * 4 + j;
      ushort hh = f32_to_bf16_rtn(v);
      Qh[idx] = hh;
      Ql[idx] = f32_to_bf16_rtn(v - __uint_as_float((unsigned)hh << 16));
    }
  }
}

// ---------------------------------------------------------------- MFMA flash attention (causal)
// Q planes [bc][t][dg], K planes [bc][t][dg], V planes TRANSPOSED [bc][dg][t]
#define AQH 0
#define AQL 8192
#define AKH 16384
#define AKL 24576
#define AVH 32768
#define AVL 40960
#define APO 49152

__global__ __launch_bounds__(256, 2) void attn2_kernel(
    const ushort* __restrict__ Qh, const ushort* __restrict__ Ql,
    const ushort* __restrict__ Kh, const ushort* __restrict__ Kl,
    const ushort* __restrict__ Vh, const ushort* __restrict__ Vl,
    float* __restrict__ out) {
  int z = blockIdx.y;
  int qt = (int)gridDim.x - 1 - (int)blockIdx.x;   // longest blocks first
  int bc = z >> 3, h = z & 7;
  __shared__ __align__(16) char lds[57344];
  int tid = threadIdx.x, lane = tid & 63, wid = tid >> 6;
  int fr = lane & 15, fg = lane >> 4;
  int swz = (lane & 7) << 4;

  const i64 IMG2 = 262144;
  const char* bQh = (const char*)(Qh + (i64)bc * IMG2) + (i64)(qt * 64) * 1024 + h * 128;
  const char* bQl = (const char*)(Ql + (i64)bc * IMG2) + (i64)(qt * 64) * 1024 + h * 128;
  const char* bKh = (const char*)(Kh + (i64)bc * IMG2) + h * 128;
  const char* bKl = (const char*)(Kl + (i64)bc * IMG2) + h * 128;
  const char* bVh = (const char*)(Vh + (i64)bc * IMG2) + (i64)(h * 64) * 1024;
  const char* bVl = (const char*)(Vl + (i64)bc * IMG2) + (i64)(h * 64) * 1024;

  int srow = tid >> 3;              // 0..31
  int scol = (tid & 7) * 16;        // 0..112

  // stage Q once
  #pragma unroll
  for (int i = 0; i < 2; ++i) {
    int rr = i * 32 + srow;
    int cc = scol ^ ((rr & 7) << 4);
    gload_lds16(bQh + (i64)rr * 1024 + cc, lds + AQH + i * 4096 + wid * 1024);
    gload_lds16(bQl + (i64)rr * 1024 + cc, lds + AQL + i * 4096 + wid * 1024);
  }

  float m_i[4], l_i[4];
  f32x4 acc[4] = {};
  #pragma unroll
  for (int q = 0; q < 4; ++q) { m_i[q] = -3e38f; l_i[q] = 0.f; }

  for (int st = 0; st <= qt; ++st) {
    __syncthreads();   // prior tile's LDS reads done
    #pragma unroll
    for (int i = 0; i < 2; ++i) {
      int rr = i * 32 + srow;
      int cc = scol ^ ((rr & 7) << 4);
      gload_lds16(bKh + (i64)(st * 64 + rr) * 1024 + cc, lds + AKH + i * 4096 + wid * 1024);
      gload_lds16(bKl + (i64)(st * 64 + rr) * 1024 + cc, lds + AKL + i * 4096 + wid * 1024);
      gload_lds16(bVh + (i64)rr * 1024 + st * 128 + cc, lds + AVH + i * 4096 + wid * 1024);
      gload_lds16(bVl + (i64)rr * 1024 + st * 128 + cc, lds + AVL + i * 4096 + wid * 1024);
    }
    __syncthreads();   // staging drained (vmcnt 0)

    // ---- S = Q @ K^T (3-MFMA split) ----
    f32x4 sv[4] = {};
    #pragma unroll
    for (int ks = 0; ks < 2; ++ks) {
      int ko = (ks * 64 + fg * 16) ^ swz;
      bf16x8 aH = *(const bf16x8*)(lds + AQH + (wid * 16 + fr) * 128 + ko);
      bf16x8 aL = *(const bf16x8*)(lds + AQL + (wid * 16 + fr) * 128 + ko);
      #pragma unroll
      for (int f = 0; f < 4; ++f) {
        bf16x8 bH = *(const bf16x8*)(lds + AKH + (f * 16 + fr) * 128 + ko);
        bf16x8 bL = *(const bf16x8*)(lds + AKL + (f * 16 + fr) * 128 + ko);
        sv[f] = __builtin_amdgcn_mfma_f32_16x16x32_bf16(aH, bH, sv[f], 0, 0, 0);
        sv[f] = __builtin_amdgcn_mfma_f32_16x16x32_bf16(aH, bL, sv[f], 0, 0, 0);
        sv[f] = __builtin_amdgcn_mfma_f32_16x16x32_bf16(aL, bH, sv[f], 0, 0, 0);
      }
    }

    // ---- scale + causal mask ----
    #pragma unroll
    for (int f = 0; f < 4; ++f)
      #pragma unroll
      for (int q = 0; q < 4; ++q) {
        float x = sv[f][q] * 0.125f;
        if (st == qt && (f * 16 + fr) > (wid * 16 + fg * 4 + q)) x = -3e38f;
        sv[f][q] = x;
      }

    // ---- online softmax (row stats across 16-lane groups) ----
    float rm[4];
    #pragma unroll
    for (int q = 0; q < 4; ++q)
      rm[q] = fmaxf(fmaxf(sv[0][q], sv[1][q]), fmaxf(sv[2][q], sv[3][q]));
    #pragma unroll
    for (int off = 8; off >= 1; off >>= 1)
      #pragma unroll
      for (int q = 0; q < 4; ++q)
        rm[q] = fmaxf(rm[q], __shfl_xor(rm[q], off));

    float alpha[4], rs[4], pv[4][4];
    #pragma unroll
    for (int q = 0; q < 4; ++q) {
      float mn = fmaxf(m_i[q], rm[q]);
      alpha[q] = __expf(m_i[q] - mn);
      m_i[q] = mn;
      rs[q] = 0.f;
      #pragma unroll
      for (int f = 0; f < 4; ++f) {
        float p = __expf(sv[f][q] - mn);
        pv[f][q] = p;
        rs[q] += p;
      }
    }
    #pragma unroll
    for (int off = 8; off >= 1; off >>= 1)
      #pragma unroll
      for (int q = 0; q < 4; ++q)
        rs[q] += __shfl_xor(rs[q], off);
    #pragma unroll
    for (int q = 0; q < 4; ++q) {
      l_i[q] = l_i[q] * alpha[q] + rs[q];
      #pragma unroll
      for (int fd = 0; fd < 4; ++fd)
        acc[fd][q] *= alpha[q];
    }

    // ---- P -> LDS bf16 (wave-private rows; no barrier needed) ----
    #pragma unroll
    for (int f = 0; f < 4; ++f)
      #pragma unroll
      for (int q = 0; q < 4; ++q) {
        int tl = wid * 16 + fg * 4 + q;
        *(ushort*)(lds + APO + tl * 128 + ((f * 32 + fr * 2) ^ ((tl & 7) << 4))) =
            f32_to_bf16_rtn(pv[f][q]);
      }

    // ---- O += P @ V (V split hi/lo) ----
    #pragma unroll
    for (int ks = 0; ks < 2; ++ks) {
      int ko = (ks * 64 + fg * 16) ^ swz;
      bf16x8 pa = *(const bf16x8*)(lds + APO + (wid * 16 + fr) * 128 + ko);
      #pragma unroll
      for (int fd = 0; fd < 4; ++fd) {
        bf16x8 vh = *(const bf16x8*)(lds + AVH + (fd * 16 + fr) * 128 + ko);
        bf16x8 vl = *(const bf16x8*)(lds + AVL + (fd * 16 + fr) * 128 + ko);
        acc[fd] = __builtin_amdgcn_mfma_f32_16x16x32_bf16(pa, vh, acc[fd], 0, 0, 0);
        acc[fd] = __builtin_amdgcn_mfma_f32_16x16x32_bf16(pa, vl, acc[fd], 0, 0, 0);
      }
    }
  }

  // ---- epilogue ----
  #pragma unroll
  for (int q = 0; q < 4; ++q) {
    float inv = 1.f / l_i[q];
    int t = qt * 64 + wid * 16 + fg * 4 + q;
    #pragma unroll
    for (int fd = 0; fd < 4; ++fd)
      out[((i64)bc * FULL + t) * FULL + h * 64 + fd * 16 + fr] = acc[fd][q] * inv;
  }
}

// ---------------------------------------------------------------- launch
extern "C" void kernel_launch(void* const* d_in, const int* in_sizes, int n_in,
                              void* d_out, int out_size, void* d_ws, size_t ws_size,
                              hipStream_t stream) {
  const float* idx_i  = (const float*)d_in[0];
  const float* idx_t  = (const float*)d_in[1];
  const float* idx_ir = (const float*)d_in[2];
  const float* Wli = (const float*)d_in[3];
  const float* bli = (const float*)d_in[4];
  const float* Wlt = (const float*)d_in[5];
  const float* blt = (const float*)d_in[6];
  const float* Wlir = (const float*)d_in[7];
  const float* blir = (const float*)d_in[8];
  const float* Wlo = (const float*)d_in[9];
  const float* blo = (const float*)d_in[10];
  const float* Wp  = (const float*)d_in[11];
  const float* bp  = (const float*)d_in[12];
  const float* Wk  = (const float*)d_in[13];
  const float* bk  = (const float*)d_in[14];
  const float* Wpi = (const float*)d_in[15];
  const float* bpi = (const float*)d_in[16];
  const float* Wki = (const float*)d_in[17];
  const float* bki = (const float*)d_in[18];
  const float* Wv  = (const float*)d_in[19];
  const float* bv  = (const float*)d_in[20];

  const i64 PL = (i64)NBC * FULL * FULL;      // plane slab (ushorts) = 12.58 MB
  const i64 WPL = (i64)FULL * FULL;
  ushort* U = (ushort*)d_ws;
  ushort* slab[8];
  for (int s = 0; s < 8; ++s) slab[s] = U + (i64)s * PL;
  ushort* wreg = U + 8 * PL;
  ushort* WT[8][2];
  for (int w = 0; w < 8; ++w)
    for (int p = 0; p < 2; ++p) WT[w][p] = wreg + (i64)(w * 2 + p) * WPL;
  float* Mbuf = (float*)(wreg + 16 * WPL);

  dim3 blk(256);
  dim3 gGemm(4, 4, NBC);
  const i64 AS = (i64)FULL * FULL;

  // ---- weight prep ----
  const float* Wbig[4] = {Wli, Wlt, Wlir, Wlo};
  for (int w = 0; w < 4; ++w)
    transposeSplitW<<<dim3(8, 8, 1), blk, 0, stream>>>(Wbig[w], WT[w][0], WT[w][1],
                                                       512, 512, 0, 0);
  const float* Whead[4] = {Wk, Wki, Wp, Wv};
  for (int w = 0; w < 4; ++w)
    transposeSplitW<<<dim3(1, 8, 8), blk, 0, stream>>>(Whead[w], WT[4 + w][0], WT[4 + w][1],
                                                       64, 512, 512 * 64, 64 * 512);

  // ---- input splits: x->(0,1), idx_t->(2,3), idx_ir->(4,5) ----
  add3_split<<<2048, blk, 0, stream>>>((const float4*)idx_i, (const float4*)idx_t,
                                       (const float4*)idx_ir,
                                       (ushort4*)slab[0], (ushort4*)slab[1],
                                       (ushort4*)slab[2], (ushort4*)slab[3],
                                       (ushort4*)slab[4], (ushort4*)slab[5], (int)(PL / 4));

  // xi = x@Wli + bli -> (6,7)
  gemm_split<<<gGemm, blk, 0, stream>>>(slab[0], slab[1], WT[0][0], WT[0][1], bli,
                                        nullptr, slab[6], slab[7], 512, 512, AS, 1, 0, AS, 0);
  // xt = idx_t@Wlt + blt -> (0,1)
  gemm_split<<<gGemm, blk, 0, stream>>>(slab[2], slab[3], WT[1][0], WT[1][1], blt,
                                        nullptr, slab[0], slab[1], 512, 512, AS, 1, 0, AS, 0);
  // key = xt@Wk + bk -> fp32 d_out
  gemm_split<<<gGemm, blk, 0, stream>>>(slab[0], slab[1], WT[4][0], WT[4][1], bk,
                                        (float*)d_out, nullptr, nullptr, 512, 512, AS, 1, 0, AS, 0);
  // M = key^T @ Wpi
  mh_kernel<<<192, blk, 0, stream>>>((const float*)d_out, Wpi, Mbuf);
  // xt -> xtT in place (0,1)
  transposeIP<<<dim3(8, 8, 48), blk, 0, stream>>>(slab[0], slab[1], AS);
  // xir = idx_ir@Wlir + blir -> (2,3)
  gemm_split<<<gGemm, blk, 0, stream>>>(slab[4], slab[5], WT[2][0], WT[2][1], blir,
                                        nullptr, slab[2], slab[3], 512, 512, AS, 1, 0, AS, 0);
  // t1 = xi@xtT -> (4,5)
  gemm_split<<<gGemm, blk, 0, stream>>>(slab[6], slab[7], slab[0], slab[1], nullptr,
                                        nullptr, slab[4], slab[5], 512, 512, AS, NBC, AS, AS, 0);
  // keyi = xir@Wki + bki -> SPLIT planes (0,1)   [xtT dead]
  gemm_split<<<gGemm, blk, 0, stream>>>(slab[2], slab[3], WT[5][0], WT[5][1], bki,
                                        nullptr, slab[0], slab[1], 512, 512, AS, 1, 0, AS, 0);
  // xir -> xirT in place (2,3)
  transposeIP<<<dim3(8, 8, 48), blk, 0, stream>>>(slab[2], slab[3], AS);
  // t2 = t1@xirT -> (6,7)   [xi dead]
  gemm_split<<<gGemm, blk, 0, stream>>>(slab[4], slab[5], slab[2], slab[3], nullptr,
                                        nullptr, slab[6], slab[7], 512, 512, AS, NBC, AS, AS, 0);
  // xi2 = t2@Wlo + blo -> (2,3)   [xirT dead]
  gemm_split<<<gGemm, blk, 0, stream>>>(slab[6], slab[7], WT[3][0], WT[3][1], blo,
                                        nullptr, slab[2], slab[3], 512, 512, AS, 1, 0, AS, 0);
  // pos = xi2@Wp + bp -> fp32 (4,5)   [t1 dead]
  float* pos = (float*)slab[4];
  gemm_split<<<gGemm, blk, 0, stream>>>(slab[2], slab[3], WT[6][0], WT[6][1], bp,
                                        pos, nullptr, nullptr, 512, 512, AS, 1, 0, AS, 0);
  // valT = xi2@Wv + bv -> split planes TRANSPOSED (6,7)   [t2 dead]
  gemm_split<<<gGemm, blk, 0, stream>>>(slab[2], slab[3], WT[7][0], WT[7][1], bv,
                                        nullptr, slab[6], slab[7], 512, 512, AS, 1, 0, AS, 1);
  // q2 = 0.125*pos@M + bpi -> split planes (2,3)   [xi2 dead]
  q2_split_kernel<<<dim3(8, 192), blk, 0, stream>>>(pos, Mbuf, bpi, slab[2], slab[3]);
  // attention: Q(2,3), K(0,1), V^T(6,7) -> d_out
  attn2_kernel<<<dim3(8, 192), blk, 0, stream>>>(slab[2], slab[3], slab[0], slab[1],
                                                 slab[6], slab[7], (float*)d_out);
}

// Round 4
// 486.645 us; speedup vs baseline: 2.4783x; 1.0789x over previous
//
#include <hip/hip_runtime.h>

typedef long long i64;
typedef __attribute__((ext_vector_type(4))) float f32x4;
typedef __attribute__((ext_vector_type(8))) __bf16 bf16x8;

#define FULL 512
#define NBC  24   // B*C = 8*3

__device__ __forceinline__ void gload_lds16(const void* g, void* l) {
  __builtin_amdgcn_global_load_lds(
      (const __attribute__((address_space(1))) void*)g,
      (__attribute__((address_space(3))) void*)l, 16, 0, 0);
}

__device__ __forceinline__ ushort f32_to_bf16_rtn(float x) {
  unsigned u = __float_as_uint(x);
  return (ushort)((u + 0x7FFFu + ((u >> 16) & 1u)) >> 16);
}

// ---------------------------------------------------------------- add3 + split inputs
__global__ __launch_bounds__(256) void add3_split(
    const float4* __restrict__ a, const float4* __restrict__ b, const float4* __restrict__ c,
    ushort4* __restrict__ xh, ushort4* __restrict__ xl,
    ushort4* __restrict__ bh, ushort4* __restrict__ bl,
    ushort4* __restrict__ ch, ushort4* __restrict__ cl, int n4) {
  int i = blockIdx.x * 256 + threadIdx.x;
  int stride = gridDim.x * 256;
  for (; i < n4; i += stride) {
    float4 va = a[i], vb = b[i], vc = c[i];
    float xs[4] = {va.x + vb.x + vc.x, va.y + vb.y + vc.y,
                   va.z + vb.z + vc.z, va.w + vb.w + vc.w};
    float bs[4] = {vb.x, vb.y, vb.z, vb.w};
    float cs[4] = {vc.x, vc.y, vc.z, vc.w};
    ushort4 h, l;
    ushort* hp = (ushort*)&h; ushort* lp = (ushort*)&l;
    #pragma unroll
    for (int k = 0; k < 4; ++k) {
      ushort hh = f32_to_bf16_rtn(xs[k]); hp[k] = hh;
      lp[k] = f32_to_bf16_rtn(xs[k] - __uint_as_float((unsigned)hh << 16));
    }
    xh[i] = h; xl[i] = l;
    #pragma unroll
    for (int k = 0; k < 4; ++k) {
      ushort hh = f32_to_bf16_rtn(bs[k]); hp[k] = hh;
      lp[k] = f32_to_bf16_rtn(bs[k] - __uint_as_float((unsigned)hh << 16));
    }
    bh[i] = h; bl[i] = l;
    #pragma unroll
    for (int k = 0; k < 4; ++k) {
      ushort hh = f32_to_bf16_rtn(cs[k]); hp[k] = hh;
      lp[k] = f32_to_bf16_rtn(cs[k] - __uint_as_float((unsigned)hh << 16));
    }
    ch[i] = h; cl[i] = l;
  }
}

// ---------------------------------------------------------------- fused transpose+split for 4 weights (1 dispatch)
__global__ __launch_bounds__(256) void transposeSplitW4(
    const float* __restrict__ p0, const float* __restrict__ p1,
    const float* __restrict__ p2, const float* __restrict__ p3,
    ushort* __restrict__ wreg, int heads) {
  const float* ins[4] = {p0, p1, p2, p3};
  const i64 WPL = 262144;
  int w, inLD; i64 inOff, outOff;
  if (!heads) {
    w = blockIdx.z; inLD = 512; inOff = 0; outOff = (i64)(2 * w) * WPL;
  } else {
    w = blockIdx.z >> 3; int b = blockIdx.z & 7; inLD = 64;
    inOff = (i64)b * 512 * 64; outOff = (i64)(2 * (4 + w)) * WPL + (i64)b * 64 * 512;
  }
  const float* I = ins[w] + inOff;
  ushort* outH = wreg + outOff;
  ushort* outL = outH + WPL;
  int r0 = blockIdx.y * 64, c0 = blockIdx.x * 64;
  __shared__ ushort sH[64][68];
  __shared__ ushort sL[64][68];
  int tid = threadIdx.x, tx = tid & 15, ty = tid >> 4;
  #pragma unroll
  for (int it = 0; it < 4; ++it) {
    int r = it * 16 + ty;
    float4 v = *(const float4*)&I[(i64)(r0 + r) * inLD + c0 + tx * 4];
    float vs[4] = {v.x, v.y, v.z, v.w};
    #pragma unroll
    for (int k = 0; k < 4; ++k) {
      ushort hh = f32_to_bf16_rtn(vs[k]);
      sH[tx * 4 + k][r] = hh;
      sL[tx * 4 + k][r] = f32_to_bf16_rtn(vs[k] - __uint_as_float((unsigned)hh << 16));
    }
  }
  __syncthreads();
  #pragma unroll
  for (int it = 0; it < 4; ++it) {
    int c = it * 16 + ty;
    ushort4 hv, lv;
    ushort* hp = (ushort*)&hv; ushort* lp = (ushort*)&lv;
    #pragma unroll
    for (int k = 0; k < 4; ++k) { hp[k] = sH[c][tx * 4 + k]; lp[k] = sL[c][tx * 4 + k]; }
    i64 off = (i64)(c0 + c) * 512 + r0 + tx * 4;
    *(ushort4*)&outH[off] = hv;
    *(ushort4*)&outL[off] = lv;
  }
}

// ---------------------------------------------------------------- in-place bf16 transpose (512x512, batched)
__global__ __launch_bounds__(256) void transposeIP(ushort* __restrict__ hi, ushort* __restrict__ lo,
                                                   i64 batch) {
  int bi = blockIdx.x, bj = blockIdx.y;
  if (bi > bj) return;
  int z = blockIdx.z;
  ushort* buf = ((z & 1) ? lo : hi) + (i64)(z >> 1) * batch;
  __shared__ ushort tA[64][68];
  __shared__ ushort tB[64][68];
  int tid = threadIdx.x, tx = tid & 15, ty = tid >> 4;
  #pragma unroll
  for (int it = 0; it < 4; ++it) {
    int r = it * 16 + ty;
    ushort4 a = *(const ushort4*)&buf[(i64)(bi * 64 + r) * 512 + bj * 64 + tx * 4];
    ushort* ap = (ushort*)&a;
    #pragma unroll
    for (int k = 0; k < 4; ++k) tA[tx * 4 + k][r] = ap[k];
    if (bi != bj) {
      ushort4 b = *(const ushort4*)&buf[(i64)(bj * 64 + r) * 512 + bi * 64 + tx * 4];
      ushort* bp = (ushort*)&b;
      #pragma unroll
      for (int k = 0; k < 4; ++k) tB[tx * 4 + k][r] = bp[k];
    }
  }
  __syncthreads();
  #pragma unroll
  for (int it = 0; it < 4; ++it) {
    int c = it * 16 + ty;
    ushort4 v; ushort* vp = (ushort*)&v;
    #pragma unroll
    for (int k = 0; k < 4; ++k) vp[k] = tA[c][tx * 4 + k];
    *(ushort4*)&buf[(i64)(bj * 64 + c) * 512 + bi * 64 + tx * 4] = v;
    if (bi != bj) {
      #pragma unroll
      for (int k = 0; k < 4; ++k) vp[k] = tB[c][tx * 4 + k];
      *(ushort4*)&buf[(i64)(bi * 64 + c) * 512 + bj * 64 + tx * 4] = v;
    }
  }
}

// ---------------------------------------------------------------- split-bf16 MFMA GEMM (templated on 3-vs-1 MFMA)
template<int SPLIT3>
__global__ __launch_bounds__(256, 2) void gemm_t(
    const ushort* __restrict__ Ahi, const ushort* __restrict__ Alo,
    const ushort* __restrict__ Bhi, const ushort* __restrict__ Blo,
    const float* __restrict__ bias, i64 biasStride,
    float* __restrict__ Cf, ushort* __restrict__ Chi, ushort* __restrict__ Clo,
    int K, int N, i64 aStride, int bMod, i64 bStride, i64 cStride, int transC) {
  int z = blockIdx.z;
  int m0 = blockIdx.y * 128, n0 = blockIdx.x * 128;
  const ushort* Ah = Ahi + (i64)z * aStride + (i64)m0 * K;
  const ushort* Al = Alo + (i64)z * aStride + (i64)m0 * K;
  const ushort* Bh = Bhi + (i64)(z % bMod) * bStride + (i64)n0 * K;
  const ushort* Bl = Blo + (i64)(z % bMod) * bStride + (i64)n0 * K;

  constexpr int OB = SPLIT3 ? 32768 : 16384;   // B-plane byte offset
  __shared__ ushort lds[(SPLIT3 ? 4 : 2) * 128 * 64];

  int tid = threadIdx.x;
  int lane = tid & 63, wid = tid >> 6;
  int wr = wid >> 1, wc = wid & 1;

  f32x4 acc[4][4] = {};

  for (int k0 = 0; k0 < K; k0 += 64) {
    __syncthreads();
    #pragma unroll
    for (int it = 0; it < 4; ++it) {
      int s = it * 4096 + tid * 16;
      int row = s >> 7;
      int cb = (s & 127) ^ ((row & 7) << 4);
      i64 gofs = (i64)row * (K * 2) + k0 * 2 + cb;
      char* l = (char*)lds + it * 4096 + wid * 1024;
      gload_lds16((const char*)Ah + gofs, l);
      if constexpr (SPLIT3) gload_lds16((const char*)Al + gofs, l + 16384);
      gload_lds16((const char*)Bh + gofs, l + OB);
      if constexpr (SPLIT3) gload_lds16((const char*)Bl + gofs, l + OB + 16384);
    }
    __syncthreads();
    #pragma unroll
    for (int ks = 0; ks < 2; ++ks) {
      bf16x8 aH[4], aL[4], bH[4], bL[4];
      #pragma unroll
      for (int i = 0; i < 4; ++i) {
        int row = wr * 64 + i * 16 + (lane & 15);
        int cb = (ks * 64 + (lane >> 4) * 16) ^ ((row & 7) << 4);
        aH[i] = *(const bf16x8*)((const char*)lds + row * 128 + cb);
        if constexpr (SPLIT3)
          aL[i] = *(const bf16x8*)((const char*)lds + 16384 + row * 128 + cb);
      }
      #pragma unroll
      for (int j = 0; j < 4; ++j) {
        int row = wc * 64 + j * 16 + (lane & 15);
        int cb = (ks * 64 + (lane >> 4) * 16) ^ ((row & 7) << 4);
        bH[j] = *(const bf16x8*)((const char*)lds + OB + row * 128 + cb);
        if constexpr (SPLIT3)
          bL[j] = *(const bf16x8*)((const char*)lds + OB + 16384 + row * 128 + cb);
      }
      #pragma unroll
      for (int i = 0; i < 4; ++i)
        #pragma unroll
        for (int j = 0; j < 4; ++j) {
          acc[i][j] = __builtin_amdgcn_mfma_f32_16x16x32_bf16(aH[i], bH[j], acc[i][j], 0, 0, 0);
          if constexpr (SPLIT3) {
            acc[i][j] = __builtin_amdgcn_mfma_f32_16x16x32_bf16(aH[i], bL[j], acc[i][j], 0, 0, 0);
            acc[i][j] = __builtin_amdgcn_mfma_f32_16x16x32_bf16(aL[i], bH[j], acc[i][j], 0, 0, 0);
          }
        }
    }
  }

  int colBase = n0 + wc * 64 + (lane & 15);
  int rowBase = m0 + wr * 64 + (lane >> 4) * 4;
  #pragma unroll
  for (int j = 0; j < 4; ++j) {
    int col = colBase + j * 16;
    float bv = bias ? bias[(i64)z * biasStride + col] : 0.f;
    #pragma unroll
    for (int i = 0; i < 4; ++i) {
      if (transC && Chi && !Clo && !Cf) {
        // vectorized hi-only transposed store (consecutive rows)
        ushort4 hv; ushort* hp = (ushort*)&hv;
        #pragma unroll
        for (int q = 0; q < 4; ++q) hp[q] = f32_to_bf16_rtn(acc[i][j][q] + bv);
        int row = rowBase + i * 16;
        *(ushort4*)&Chi[(i64)z * cStride + (i64)col * N + row] = hv;
      } else {
        #pragma unroll
        for (int q = 0; q < 4; ++q) {
          int row = rowBase + i * 16 + q;
          i64 idx = (i64)z * cStride +
                    (transC ? ((i64)col * N + row) : ((i64)row * N + col));
          float v = acc[i][j][q] + bv;
          if (Cf) Cf[idx] = v;
          if (Chi) {
            ushort hh = f32_to_bf16_rtn(v);
            Chi[idx] = hh;
            if (Clo) Clo[idx] = f32_to_bf16_rtn(v - __uint_as_float((unsigned)hh << 16));
          }
        }
      }
    }
  }
}

// ---------------------------------------------------------------- M = key[:,hblk]^T @ Wpi[h]  (fp32)
__global__ __launch_bounds__(256) void mh_kernel(const float* __restrict__ key,
                                                 const float* __restrict__ Wpi,
                                                 float* __restrict__ M) {
  int z = blockIdx.x, bc = z >> 3, h = z & 7;
  const float* Kb = key + (i64)bc * FULL * FULL + h * 64;
  const float* Wb = Wpi + (i64)h * FULL * 64;
  float* Mb = M + (i64)z * 64 * 64;

  __shared__ float sK[64][68];
  __shared__ float sW[64][68];

  int tid = threadIdx.x, tx = tid & 15, ty = tid >> 4;
  float acc[4][4] = {};

  for (int s0 = 0; s0 < FULL; s0 += 64) {
    __syncthreads();
    #pragma unroll
    for (int it = 0; it < 4; ++it) {
      int idx = tid + it * 256;
      int r = idx >> 4, c4 = idx & 15;
      *(float4*)&sK[r][c4 * 4] = *(const float4*)&Kb[(i64)(s0 + r) * FULL + c4 * 4];
      *(float4*)&sW[r][c4 * 4] = *(const float4*)&Wb[(i64)(s0 + r) * 64 + c4 * 4];
    }
    __syncthreads();
    for (int s = 0; s < 64; ++s) {
      float4 a4 = *(const float4*)&sK[s][ty * 4];
      float4 b4 = *(const float4*)&sW[s][tx * 4];
      float av[4] = {a4.x, a4.y, a4.z, a4.w};
      float bv[4] = {b4.x, b4.y, b4.z, b4.w};
      #pragma unroll
      for (int i = 0; i < 4; ++i)
        #pragma unroll
        for (int j = 0; j < 4; ++j)
          acc[i][j] += av[i] * bv[j];
    }
  }
  #pragma unroll
  for (int i = 0; i < 4; ++i)
    #pragma unroll
    for (int j = 0; j < 4; ++j)
      Mb[(ty * 4 + i) * 64 + tx * 4 + j] = acc[i][j];
}

// ---------------------------------------------------------------- WpmT[bc][h*64+d][s] = 0.125*(M^T @ Wp^T) -> split
__global__ __launch_bounds__(256) void wpm_kernel(
    const float* __restrict__ M, const ushort* __restrict__ WpTh, const ushort* __restrict__ WpTl,
    ushort* __restrict__ outH, ushort* __restrict__ outL) {
  int z = blockIdx.y, h = z & 7;
  int s0 = blockIdx.x * 128;
  __shared__ float sM[64][65];    // sM[e][d]
  __shared__ float sW[64][132];   // sW[e][s]
  int tid = threadIdx.x;
  const float* Mb = M + (i64)z * 4096;
  for (int i = 0; i < 16; ++i) {
    int idx = i * 256 + tid;
    sM[idx >> 6][idx & 63] = Mb[idx];
  }
  for (int i = 0; i < 32; ++i) {
    int idx = i * 256 + tid;
    int e = idx >> 7, s = idx & 127;
    i64 g = (i64)(h * 64 + e) * 512 + s0 + s;
    sW[e][s] = __uint_as_float((unsigned)WpTh[g] << 16) +
               __uint_as_float((unsigned)WpTl[g] << 16);
  }
  __syncthreads();
  i64 obase = (i64)(z >> 3) * ((i64)FULL * FULL) + (i64)(h * 64) * 512 + s0;
  for (int i = 0; i < 32; ++i) {
    int idx = i * 256 + tid;
    int d = idx >> 7, s = idx & 127;
    float a = 0.f;
    #pragma unroll
    for (int e = 0; e < 64; ++e) a += sM[e][d] * sW[e][s];
    float v = 0.125f * a;
    i64 o = obase + (i64)d * 512 + s;
    ushort hh = f32_to_bf16_rtn(v);
    outH[o] = hh;
    outL[o] = f32_to_bf16_rtn(v - __uint_as_float((unsigned)hh << 16));
  }
}

// ---------------------------------------------------------------- fused bias2[bc][col] = 0.125*bp@M + bpi
__global__ __launch_bounds__(256) void bias2_kernel(
    const float* __restrict__ M, const float* __restrict__ bp,
    const float* __restrict__ bpi, float* __restrict__ b2) {
  int idx = blockIdx.x * 256 + threadIdx.x;
  if (idx >= NBC * FULL) return;
  int bc = idx >> 9, col = idx & 511;
  int h = col >> 6, d = col & 63;
  const float* Mb = M + ((i64)(bc * 8 + h)) * 4096;
  float s = 0.f;
  for (int e = 0; e < 64; ++e) s += bp[h * 64 + e] * Mb[e * 64 + d];
  b2[idx] = 0.125f * s + bpi[col];
}

// ---------------------------------------------------------------- MFMA flash attention, QBLK=128
// Q,K planes [bc][t][512 col], V^T plane [bc][d_global][t]
#define BQH 0
#define BQL 16384
#define BKH 32768
#define BKL 40960
#define BVH 49152
#define BPO 57344

__global__ __launch_bounds__(256, 2) void attn3_kernel(
    const ushort* __restrict__ Qh, const ushort* __restrict__ Ql,
    const ushort* __restrict__ Kh, const ushort* __restrict__ Kl,
    const ushort* __restrict__ Vh, float* __restrict__ out) {
  int z = blockIdx.y;
  int qt = 3 - (int)blockIdx.x;          // longest blocks first
  int bc = z >> 3, h = z & 7;
  __shared__ __align__(16) char lds[73728];
  int tid = threadIdx.x, lane = tid & 63, wid = tid >> 6;
  int fr = lane & 15, fg = lane >> 4;
  int swz = (fr & 7) << 4;

  const i64 IMG2 = 262144;
  const char* bQh = (const char*)(Qh + (i64)bc * IMG2) + (i64)(qt * 128) * 1024 + h * 128;
  const char* bQl = (const char*)(Ql + (i64)bc * IMG2) + (i64)(qt * 128) * 1024 + h * 128;
  const char* bKh = (const char*)(Kh + (i64)bc * IMG2) + h * 128;
  const char* bKl = (const char*)(Kl + (i64)bc * IMG2) + h * 128;
  const char* bVT = (const char*)(Vh + (i64)bc * IMG2) + (i64)(h * 64) * 1024;

  int srow = tid >> 3, scolb = (tid & 7) * 16;

  // stage Q (128 rows x 128B, hi+lo)
  #pragma unroll
  for (int i = 0; i < 4; ++i) {
    int rr = i * 32 + srow;
    int cc = scolb ^ ((rr & 7) << 4);
    gload_lds16(bQh + (i64)rr * 1024 + cc, lds + BQH + i * 4096 + wid * 1024);
    gload_lds16(bQl + (i64)rr * 1024 + cc, lds + BQL + i * 4096 + wid * 1024);
  }

  float m_i[2][4], l_i[2][4];
  f32x4 acc[2][4] = {};
  #pragma unroll
  for (int qf = 0; qf < 2; ++qf)
    #pragma unroll
    for (int q = 0; q < 4; ++q) { m_i[qf][q] = -3e38f; l_i[qf][q] = 0.f; }

  int nst = 2 * qt + 2;
  for (int st = 0; st < nst; ++st) {
    __syncthreads();
    #pragma unroll
    for (int i = 0; i < 2; ++i) {
      int rr = i * 32 + srow;
      int cc = scolb ^ ((rr & 7) << 4);
      gload_lds16(bKh + (i64)(st * 64 + rr) * 1024 + cc, lds + BKH + i * 4096 + wid * 1024);
      gload_lds16(bKl + (i64)(st * 64 + rr) * 1024 + cc, lds + BKL + i * 4096 + wid * 1024);
      gload_lds16(bVT + (i64)rr * 1024 + st * 128 + cc, lds + BVH + i * 4096 + wid * 1024);
    }
    __syncthreads();

    // ---- S = Q @ K^T (3-MFMA split) ----
    f32x4 sv[2][4] = {};
    __builtin_amdgcn_s_setprio(1);
    #pragma unroll
    for (int ks = 0; ks < 2; ++ks) {
      int ko = (ks * 64 + fg * 16) ^ swz;
      bf16x8 aH[2], aL[2];
      #pragma unroll
      for (int qf = 0; qf < 2; ++qf) {
        aH[qf] = *(const bf16x8*)(lds + BQH + (wid * 32 + qf * 16 + fr) * 128 + ko);
        aL[qf] = *(const bf16x8*)(lds + BQL + (wid * 32 + qf * 16 + fr) * 128 + ko);
      }
      #pragma unroll
      for (int f = 0; f < 4; ++f) {
        bf16x8 bH = *(const bf16x8*)(lds + BKH + (f * 16 + fr) * 128 + ko);
        bf16x8 bL = *(const bf16x8*)(lds + BKL + (f * 16 + fr) * 128 + ko);
        #pragma unroll
        for (int qf = 0; qf < 2; ++qf) {
          sv[qf][f] = __builtin_amdgcn_mfma_f32_16x16x32_bf16(aH[qf], bH, sv[qf][f], 0, 0, 0);
          sv[qf][f] = __builtin_amdgcn_mfma_f32_16x16x32_bf16(aH[qf], bL, sv[qf][f], 0, 0, 0);
          sv[qf][f] = __builtin_amdgcn_mfma_f32_16x16x32_bf16(aL[qf], bH, sv[qf][f], 0, 0, 0);
        }
      }
    }
    __builtin_amdgcn_s_setprio(0);

    // ---- scale + causal mask ----
    #pragma unroll
    for (int qf = 0; qf < 2; ++qf)
      #pragma unroll
      for (int f = 0; f < 4; ++f)
        #pragma unroll
        for (int q = 0; q < 4; ++q) {
          float x = sv[qf][f][q] * 0.125f;
          if (st >= 2 * qt) {
            int gq = qt * 128 + wid * 32 + qf * 16 + fg * 4 + q;
            int gk = st * 64 + f * 16 + fr;
            if (gk > gq) x = -3e38f;
          }
          sv[qf][f][q] = x;
        }

    // ---- online softmax ----
    float rm[2][4];
    #pragma unroll
    for (int qf = 0; qf < 2; ++qf)
      #pragma unroll
      for (int q = 0; q < 4; ++q)
        rm[qf][q] = fmaxf(fmaxf(sv[qf][0][q], sv[qf][1][q]), fmaxf(sv[qf][2][q], sv[qf][3][q]));
    #pragma unroll
    for (int off = 8; off >= 1; off >>= 1)
      #pragma unroll
      for (int qf = 0; qf < 2; ++qf)
        #pragma unroll
        for (int q = 0; q < 4; ++q)
          rm[qf][q] = fmaxf(rm[qf][q], __shfl_xor(rm[qf][q], off));

    float alpha[2][4], rs[2][4], pv[2][4][4];
    #pragma unroll
    for (int qf = 0; qf < 2; ++qf)
      #pragma unroll
      for (int q = 0; q < 4; ++q) {
        float mn = fmaxf(m_i[qf][q], rm[qf][q]);
        alpha[qf][q] = __expf(m_i[qf][q] - mn);
        m_i[qf][q] = mn;
        rs[qf][q] = 0.f;
        #pragma unroll
        for (int f = 0; f < 4; ++f) {
          float p = __expf(sv[qf][f][q] - mn);
          pv[qf][f][q] = p;
          rs[qf][q] += p;
        }
      }
    #pragma unroll
    for (int off = 8; off >= 1; off >>= 1)
      #pragma unroll
      for (int qf = 0; qf < 2; ++qf)
        #pragma unroll
        for (int q = 0; q < 4; ++q)
          rs[qf][q] += __shfl_xor(rs[qf][q], off);
    #pragma unroll
    for (int qf = 0; qf < 2; ++qf)
      #pragma unroll
      for (int q = 0; q < 4; ++q) {
        l_i[qf][q] = l_i[qf][q] * alpha[qf][q] + rs[qf][q];
        #pragma unroll
        for (int fd = 0; fd < 4; ++fd)
          acc[qf][fd][q] *= alpha[qf][q];
      }

    // ---- P -> LDS bf16 (wave-private rows) ----
    #pragma unroll
    for (int qf = 0; qf < 2; ++qf)
      #pragma unroll
      for (int f = 0; f < 4; ++f)
        #pragma unroll
        for (int q = 0; q < 4; ++q) {
          int tl = wid * 32 + qf * 16 + fg * 4 + q;
          *(ushort*)(lds + BPO + tl * 128 + ((f * 32 + fr * 2) ^ ((tl & 7) << 4))) =
              f32_to_bf16_rtn(pv[qf][f][q]);
        }

    // ---- O += P @ V (V hi only) ----
    __builtin_amdgcn_s_setprio(1);
    #pragma unroll
    for (int ks = 0; ks < 2; ++ks) {
      int ko = (ks * 64 + fg * 16) ^ swz;
      bf16x8 pa[2];
      #pragma unroll
      for (int qf = 0; qf < 2; ++qf)
        pa[qf] = *(const bf16x8*)(lds + BPO + (wid * 32 + qf * 16 + fr) * 128 + ko);
      #pragma unroll
      for (int fd = 0; fd < 4; ++fd) {
        bf16x8 vh = *(const bf16x8*)(lds + BVH + (fd * 16 + fr) * 128 + ko);
        #pragma unroll
        for (int qf = 0; qf < 2; ++qf)
          acc[qf][fd] = __builtin_amdgcn_mfma_f32_16x16x32_bf16(pa[qf], vh, acc[qf][fd], 0, 0, 0);
      }
    }
    __builtin_amdgcn_s_setprio(0);
  }

  // ---- epilogue ----
  #pragma unroll
  for (int qf = 0; qf < 2; ++qf)
    #pragma unroll
    for (int q = 0; q < 4; ++q) {
      float inv = 1.f / l_i[qf][q];
      int t = qt * 128 + wid * 32 + qf * 16 + fg * 4 + q;
      #pragma unroll
      for (int fd = 0; fd < 4; ++fd)
        out[((i64)bc * FULL + t) * FULL + h * 64 + fd * 16 + fr] = acc[qf][fd][q] * inv;
    }
}

// ---------------------------------------------------------------- launch
extern "C" void kernel_launch(void* const* d_in, const int* in_sizes, int n_in,
                              void* d_out, int out_size, void* d_ws, size_t ws_size,
                              hipStream_t stream) {
  const float* idx_i  = (const float*)d_in[0];
  const float* idx_t  = (const float*)d_in[1];
  const float* idx_ir = (const float*)d_in[2];
  const float* Wli = (const float*)d_in[3];
  const float* bli = (const float*)d_in[4];
  const float* Wlt = (const float*)d_in[5];
  const float* blt = (const float*)d_in[6];
  const float* Wlir = (const float*)d_in[7];
  const float* blir = (const float*)d_in[8];
  const float* Wlo = (const float*)d_in[9];
  const float* blo = (const float*)d_in[10];
  const float* Wp  = (const float*)d_in[11];
  const float* bp  = (const float*)d_in[12];
  const float* Wk  = (const float*)d_in[13];
  const float* bk  = (const float*)d_in[14];
  const float* Wpi = (const float*)d_in[15];
  const float* bpi = (const float*)d_in[16];
  const float* Wki = (const float*)d_in[17];
  const float* bki = (const float*)d_in[18];
  const float* Wv  = (const float*)d_in[19];
  const float* bv  = (const float*)d_in[20];

  const i64 PL = (i64)NBC * FULL * FULL;      // plane slab (ushorts)
  const i64 WPL = (i64)FULL * FULL;
  ushort* U = (ushort*)d_ws;
  ushort* s0 = U;            ushort* s1 = U + PL;
  ushort* s2 = U + 2 * PL;   ushort* s3 = U + 3 * PL;
  ushort* s4 = U + 4 * PL;   ushort* s5 = U + 5 * PL;
  ushort* s6 = U + 6 * PL;   ushort* s7 = U + 7 * PL;
  ushort* wreg = U + 8 * PL;
  float* Mbuf = (float*)(wreg + 16 * WPL);
  float* bias2 = Mbuf + (i64)192 * 4096;
  // d_out doubles as two ushort planes between key's death and attention
  ushort* D0 = (ushort*)d_out;
  ushort* D1 = D0 + PL;

  dim3 blk(256);
  dim3 gGemm(4, 4, NBC);
  const i64 AS = (i64)FULL * FULL;

  // ---- weight prep (2 dispatches) ----
  transposeSplitW4<<<dim3(8, 8, 4), blk, 0, stream>>>(Wli, Wlt, Wlir, Wlo, wreg, 0);
  transposeSplitW4<<<dim3(1, 8, 32), blk, 0, stream>>>(Wk, Wki, Wp, Wv, wreg, 1);

  // ---- input splits: x->(0,1), idx_t->(2,3), idx_ir->(4,5) ----
  add3_split<<<2048, blk, 0, stream>>>((const float4*)idx_i, (const float4*)idx_t,
                                       (const float4*)idx_ir,
                                       (ushort4*)s0, (ushort4*)s1,
                                       (ushort4*)s2, (ushort4*)s3,
                                       (ushort4*)s4, (ushort4*)s5, (int)(PL / 4));

  // xi = x@Wli + bli -> (6,7)
  gemm_t<1><<<gGemm, blk, 0, stream>>>(s0, s1, wreg + 0 * WPL, wreg + 1 * WPL, bli, 0,
                                       nullptr, s6, s7, 512, 512, AS, 1, 0, AS, 0);
  // xt = idx_t@Wlt + blt -> (0,1)
  gemm_t<1><<<gGemm, blk, 0, stream>>>(s2, s3, wreg + 2 * WPL, wreg + 3 * WPL, blt, 0,
                                       nullptr, s0, s1, 512, 512, AS, 1, 0, AS, 0);
  // key = xt@Wk + bk -> fp32 d_out
  gemm_t<1><<<gGemm, blk, 0, stream>>>(s0, s1, wreg + 8 * WPL, wreg + 9 * WPL, bk, 0,
                                       (float*)d_out, nullptr, nullptr, 512, 512, AS, 1, 0, AS, 0);
  // M = key^T @ Wpi
  mh_kernel<<<192, blk, 0, stream>>>((const float*)d_out, Wpi, Mbuf);
  // WpmT = 0.125 * M^T @ Wp^T -> (2,3)   [idx_t split dead]
  wpm_kernel<<<dim3(4, 192), blk, 0, stream>>>(Mbuf, wreg + 12 * WPL, wreg + 13 * WPL, s2, s3);
  // bias2 = 0.125*bp@M + bpi
  bias2_kernel<<<48, blk, 0, stream>>>(Mbuf, bp, bpi, bias2);
  // xt -> xtT in place (0,1)
  transposeIP<<<dim3(8, 8, 48), blk, 0, stream>>>(s0, s1, AS);
  // xir = idx_ir@Wlir + blir -> D0,D1 (d_out scratch; key dead)
  gemm_t<1><<<gGemm, blk, 0, stream>>>(s4, s5, wreg + 4 * WPL, wreg + 5 * WPL, blir, 0,
                                       nullptr, D0, D1, 512, 512, AS, 1, 0, AS, 0);
  // t1 = xi@xtT -> (4,5)
  gemm_t<1><<<gGemm, blk, 0, stream>>>(s6, s7, s0, s1, nullptr, 0,
                                       nullptr, s4, s5, 512, 512, AS, NBC, AS, AS, 0);
  // keyi = xir@Wki + bki -> (6,7)   [xi dead]
  gemm_t<1><<<gGemm, blk, 0, stream>>>(D0, D1, wreg + 10 * WPL, wreg + 11 * WPL, bki, 0,
                                       nullptr, s6, s7, 512, 512, AS, 1, 0, AS, 0);
  // xir -> xirT in place (D0,D1)
  transposeIP<<<dim3(8, 8, 48), blk, 0, stream>>>(D0, D1, AS);
  // t2 = t1@xirT -> (0,1)   [xtT dead]
  gemm_t<1><<<gGemm, blk, 0, stream>>>(s4, s5, D0, D1, nullptr, 0,
                                       nullptr, s0, s1, 512, 512, AS, NBC, AS, AS, 0);
  // xi2 = t2@Wlo + blo -> (4,5)   [t1 dead]
  gemm_t<1><<<gGemm, blk, 0, stream>>>(s0, s1, wreg + 6 * WPL, wreg + 7 * WPL, blo, 0,
                                       nullptr, s4, s5, 512, 512, AS, 1, 0, AS, 0);
  // q2 = xi2@WpmT + bias2 -> (0,1)   [t2 dead]
  gemm_t<1><<<gGemm, blk, 0, stream>>>(s4, s5, s2, s3, bias2, 512,
                                       nullptr, s0, s1, 512, 512, AS, NBC, AS, AS, 0);
  // valT = xi2@Wv + bv (hi only, transposed) -> (2)   [WpmT dead]
  gemm_t<0><<<gGemm, blk, 0, stream>>>(s4, s5, wreg + 14 * WPL, wreg + 15 * WPL, bv, 0,
                                       nullptr, s2, nullptr, 512, 512, AS, 1, 0, AS, 1);
  // attention: Q(0,1), K(6,7), V^T(2) -> d_out
  attn3_kernel<<<dim3(4, 192), blk, 0, stream>>>(s0, s1, s6, s7, s2, (float*)d_out);
}

// Round 5
// 478.208 us; speedup vs baseline: 2.5220x; 1.0176x over previous
//
#include <hip/hip_runtime.h>

typedef long long i64;
typedef __attribute__((ext_vector_type(4))) float f32x4;
typedef __attribute__((ext_vector_type(8))) __bf16 bf16x8;

#define FULL 512
#define NBC  24   // B*C = 8*3

__device__ __forceinline__ void gload_lds16(const void* g, void* l) {
  __builtin_amdgcn_global_load_lds(
      (const __attribute__((address_space(1))) void*)g,
      (__attribute__((address_space(3))) void*)l, 16, 0, 0);
}

__device__ __forceinline__ ushort f32_to_bf16_rtn(float x) {
  unsigned u = __float_as_uint(x);
  return (ushort)((u + 0x7FFFu + ((u >> 16) & 1u)) >> 16);
}

// ---------------------------------------------------------------- add3 + split inputs
__global__ __launch_bounds__(256) void add3_split(
    const float4* __restrict__ a, const float4* __restrict__ b, const float4* __restrict__ c,
    ushort4* __restrict__ xh, ushort4* __restrict__ xl,
    ushort4* __restrict__ bh, ushort4* __restrict__ bl,
    ushort4* __restrict__ ch, ushort4* __restrict__ cl, int n4) {
  int i = blockIdx.x * 256 + threadIdx.x;
  int stride = gridDim.x * 256;
  for (; i < n4; i += stride) {
    float4 va = a[i], vb = b[i], vc = c[i];
    float xs[4] = {va.x + vb.x + vc.x, va.y + vb.y + vc.y,
                   va.z + vb.z + vc.z, va.w + vb.w + vc.w};
    float bs[4] = {vb.x, vb.y, vb.z, vb.w};
    float cs[4] = {vc.x, vc.y, vc.z, vc.w};
    ushort4 h, l;
    ushort* hp = (ushort*)&h; ushort* lp = (ushort*)&l;
    #pragma unroll
    for (int k = 0; k < 4; ++k) {
      ushort hh = f32_to_bf16_rtn(xs[k]); hp[k] = hh;
      lp[k] = f32_to_bf16_rtn(xs[k] - __uint_as_float((unsigned)hh << 16));
    }
    xh[i] = h; xl[i] = l;
    #pragma unroll
    for (int k = 0; k < 4; ++k) {
      ushort hh = f32_to_bf16_rtn(bs[k]); hp[k] = hh;
      lp[k] = f32_to_bf16_rtn(bs[k] - __uint_as_float((unsigned)hh << 16));
    }
    bh[i] = h; bl[i] = l;
    #pragma unroll
    for (int k = 0; k < 4; ++k) {
      ushort hh = f32_to_bf16_rtn(cs[k]); hp[k] = hh;
      lp[k] = f32_to_bf16_rtn(cs[k] - __uint_as_float((unsigned)hh << 16));
    }
    ch[i] = h; cl[i] = l;
  }
}

// ---------------------------------------------------------------- fused transpose+split for 4 weights (1 dispatch)
__global__ __launch_bounds__(256) void transposeSplitW4(
    const float* __restrict__ p0, const float* __restrict__ p1,
    const float* __restrict__ p2, const float* __restrict__ p3,
    ushort* __restrict__ wreg, int heads) {
  const float* ins[4] = {p0, p1, p2, p3};
  const i64 WPL = 262144;
  int w, inLD; i64 inOff, outOff;
  if (!heads) {
    w = blockIdx.z; inLD = 512; inOff = 0; outOff = (i64)(2 * w) * WPL;
  } else {
    w = blockIdx.z >> 3; int b = blockIdx.z & 7; inLD = 64;
    inOff = (i64)b * 512 * 64; outOff = (i64)(2 * (4 + w)) * WPL + (i64)b * 64 * 512;
  }
  const float* I = ins[w] + inOff;
  ushort* outH = wreg + outOff;
  ushort* outL = outH + WPL;
  int r0 = blockIdx.y * 64, c0 = blockIdx.x * 64;
  __shared__ ushort sH[64][68];
  __shared__ ushort sL[64][68];
  int tid = threadIdx.x, tx = tid & 15, ty = tid >> 4;
  #pragma unroll
  for (int it = 0; it < 4; ++it) {
    int r = it * 16 + ty;
    float4 v = *(const float4*)&I[(i64)(r0 + r) * inLD + c0 + tx * 4];
    float vs[4] = {v.x, v.y, v.z, v.w};
    #pragma unroll
    for (int k = 0; k < 4; ++k) {
      ushort hh = f32_to_bf16_rtn(vs[k]);
      sH[tx * 4 + k][r] = hh;
      sL[tx * 4 + k][r] = f32_to_bf16_rtn(vs[k] - __uint_as_float((unsigned)hh << 16));
    }
  }
  __syncthreads();
  #pragma unroll
  for (int it = 0; it < 4; ++it) {
    int c = it * 16 + ty;
    ushort4 hv, lv;
    ushort* hp = (ushort*)&hv; ushort* lp = (ushort*)&lv;
    #pragma unroll
    for (int k = 0; k < 4; ++k) { hp[k] = sH[c][tx * 4 + k]; lp[k] = sL[c][tx * 4 + k]; }
    i64 off = (i64)(c0 + c) * 512 + r0 + tx * 4;
    *(ushort4*)&outH[off] = hv;
    *(ushort4*)&outL[off] = lv;
  }
}

// ---------------------------------------------------------------- in-place bf16 transpose (512x512, batched)
__global__ __launch_bounds__(256) void transposeIP(ushort* __restrict__ hi, ushort* __restrict__ lo,
                                                   i64 batch) {
  int bi = blockIdx.x, bj = blockIdx.y;
  if (bi > bj) return;
  int z = blockIdx.z;
  ushort* buf = ((z & 1) ? lo : hi) + (i64)(z >> 1) * batch;
  __shared__ ushort tA[64][68];
  __shared__ ushort tB[64][68];
  int tid = threadIdx.x, tx = tid & 15, ty = tid >> 4;
  #pragma unroll
  for (int it = 0; it < 4; ++it) {
    int r = it * 16 + ty;
    ushort4 a = *(const ushort4*)&buf[(i64)(bi * 64 + r) * 512 + bj * 64 + tx * 4];
    ushort* ap = (ushort*)&a;
    #pragma unroll
    for (int k = 0; k < 4; ++k) tA[tx * 4 + k][r] = ap[k];
    if (bi != bj) {
      ushort4 b = *(const ushort4*)&buf[(i64)(bj * 64 + r) * 512 + bi * 64 + tx * 4];
      ushort* bp = (ushort*)&b;
      #pragma unroll
      for (int k = 0; k < 4; ++k) tB[tx * 4 + k][r] = bp[k];
    }
  }
  __syncthreads();
  #pragma unroll
  for (int it = 0; it < 4; ++it) {
    int c = it * 16 + ty;
    ushort4 v; ushort* vp = (ushort*)&v;
    #pragma unroll
    for (int k = 0; k < 4; ++k) vp[k] = tA[c][tx * 4 + k];
    *(ushort4*)&buf[(i64)(bj * 64 + c) * 512 + bi * 64 + tx * 4] = v;
    if (bi != bj) {
      #pragma unroll
      for (int k = 0; k < 4; ++k) vp[k] = tB[c][tx * 4 + k];
      *(ushort4*)&buf[(i64)(bi * 64 + c) * 512 + bj * 64 + tx * 4] = v;
    }
  }
}

// ---------------------------------------------------------------- merged split-bf16 MFMA GEMM (two sub-problems per dispatch)
struct GDesc {
  const ushort *Ah, *Al, *Bh, *Bl;
  const float* bias;
  float* Cf; ushort* Chi; ushort* Clo;
  i64 aStride, bStride, cStride, biasStride;
  int bMod, transC, split3;
};

__global__ __launch_bounds__(256, 2) void gemm_m(GDesc dA, GDesc dB, int z0) {
  int zz = blockIdx.z;
  GDesc d = (zz < z0) ? dA : dB;
  int z = (zz < z0) ? zz : zz - z0;
  const int K = 512, N = 512;
  int m0 = blockIdx.y * 128, n0 = blockIdx.x * 128;
  const ushort* Ah = d.Ah + (i64)z * d.aStride + (i64)m0 * K;
  const ushort* Al = d.Al + (i64)z * d.aStride + (i64)m0 * K;
  const ushort* Bh = d.Bh + (i64)(z % d.bMod) * d.bStride + (i64)n0 * K;
  const ushort* Bl = d.Bl + (i64)(z % d.bMod) * d.bStride + (i64)n0 * K;

  __shared__ ushort lds[4 * 128 * 64];   // Ahi@0, Alo@16K, Bhi@32K, Blo@48K (bytes)

  int tid = threadIdx.x;
  int lane = tid & 63, wid = tid >> 6;
  int wr = wid >> 1, wc = wid & 1;

  f32x4 acc[4][4] = {};

  for (int k0 = 0; k0 < K; k0 += 64) {
    __syncthreads();
    #pragma unroll
    for (int it = 0; it < 4; ++it) {
      int s = it * 4096 + tid * 16;
      int row = s >> 7;
      int cb = (s & 127) ^ ((row & 7) << 4);
      i64 gofs = (i64)row * (K * 2) + k0 * 2 + cb;
      char* l = (char*)lds + it * 4096 + wid * 1024;
      gload_lds16((const char*)Ah + gofs, l);
      gload_lds16((const char*)Bh + gofs, l + 32768);
      if (d.split3) {
        gload_lds16((const char*)Al + gofs, l + 16384);
        gload_lds16((const char*)Bl + gofs, l + 49152);
      }
    }
    __syncthreads();
    #pragma unroll
    for (int ks = 0; ks < 2; ++ks) {
      bf16x8 aH[4], aL[4], bH[4], bL[4];
      #pragma unroll
      for (int i = 0; i < 4; ++i) {
        int row = wr * 64 + i * 16 + (lane & 15);
        int cb = (ks * 64 + (lane >> 4) * 16) ^ ((row & 7) << 4);
        aH[i] = *(const bf16x8*)((const char*)lds + row * 128 + cb);
        if (d.split3) aL[i] = *(const bf16x8*)((const char*)lds + 16384 + row * 128 + cb);
      }
      #pragma unroll
      for (int j = 0; j < 4; ++j) {
        int row = wc * 64 + j * 16 + (lane & 15);
        int cb = (ks * 64 + (lane >> 4) * 16) ^ ((row & 7) << 4);
        bH[j] = *(const bf16x8*)((const char*)lds + 32768 + row * 128 + cb);
        if (d.split3) bL[j] = *(const bf16x8*)((const char*)lds + 49152 + row * 128 + cb);
      }
      if (d.split3) {
        #pragma unroll
        for (int i = 0; i < 4; ++i)
          #pragma unroll
          for (int j = 0; j < 4; ++j) {
            acc[i][j] = __builtin_amdgcn_mfma_f32_16x16x32_bf16(aH[i], bH[j], acc[i][j], 0, 0, 0);
            acc[i][j] = __builtin_amdgcn_mfma_f32_16x16x32_bf16(aH[i], bL[j], acc[i][j], 0, 0, 0);
            acc[i][j] = __builtin_amdgcn_mfma_f32_16x16x32_bf16(aL[i], bH[j], acc[i][j], 0, 0, 0);
          }
      } else {
        #pragma unroll
        for (int i = 0; i < 4; ++i)
          #pragma unroll
          for (int j = 0; j < 4; ++j)
            acc[i][j] = __builtin_amdgcn_mfma_f32_16x16x32_bf16(aH[i], bH[j], acc[i][j], 0, 0, 0);
      }
    }
  }

  int colBase = n0 + wc * 64 + (lane & 15);
  int rowBase = m0 + wr * 64 + (lane >> 4) * 4;
  #pragma unroll
  for (int j = 0; j < 4; ++j) {
    int col = colBase + j * 16;
    float bv = d.bias ? d.bias[(i64)z * d.biasStride + col] : 0.f;
    #pragma unroll
    for (int i = 0; i < 4; ++i) {
      if (d.transC && d.Chi && !d.Clo && !d.Cf) {
        ushort4 hv; ushort* hp = (ushort*)&hv;
        #pragma unroll
        for (int q = 0; q < 4; ++q) hp[q] = f32_to_bf16_rtn(acc[i][j][q] + bv);
        int row = rowBase + i * 16;
        *(ushort4*)&d.Chi[(i64)z * d.cStride + (i64)col * N + row] = hv;
      } else {
        #pragma unroll
        for (int q = 0; q < 4; ++q) {
          int row = rowBase + i * 16 + q;
          i64 idx = (i64)z * d.cStride +
                    (d.transC ? ((i64)col * N + row) : ((i64)row * N + col));
          float v = acc[i][j][q] + bv;
          if (d.Cf) d.Cf[idx] = v;
          if (d.Chi) {
            ushort hh = f32_to_bf16_rtn(v);
            d.Chi[idx] = hh;
            if (d.Clo) d.Clo[idx] = f32_to_bf16_rtn(v - __uint_as_float((unsigned)hh << 16));
          }
        }
      }
    }
  }
}

// ---------------------------------------------------------------- M = key[:,hblk]^T @ Wpi[h]  (fp32)
__global__ __launch_bounds__(256) void mh_kernel(const float* __restrict__ key,
                                                 const float* __restrict__ Wpi,
                                                 float* __restrict__ M) {
  int z = blockIdx.x, bc = z >> 3, h = z & 7;
  const float* Kb = key + (i64)bc * FULL * FULL + h * 64;
  const float* Wb = Wpi + (i64)h * FULL * 64;
  float* Mb = M + (i64)z * 64 * 64;

  __shared__ float sK[64][68];
  __shared__ float sW[64][68];

  int tid = threadIdx.x, tx = tid & 15, ty = tid >> 4;
  float acc[4][4] = {};

  for (int s0 = 0; s0 < FULL; s0 += 64) {
    __syncthreads();
    #pragma unroll
    for (int it = 0; it < 4; ++it) {
      int idx = tid + it * 256;
      int r = idx >> 4, c4 = idx & 15;
      *(float4*)&sK[r][c4 * 4] = *(const float4*)&Kb[(i64)(s0 + r) * FULL + c4 * 4];
      *(float4*)&sW[r][c4 * 4] = *(const float4*)&Wb[(i64)(s0 + r) * 64 + c4 * 4];
    }
    __syncthreads();
    for (int s = 0; s < 64; ++s) {
      float4 a4 = *(const float4*)&sK[s][ty * 4];
      float4 b4 = *(const float4*)&sW[s][tx * 4];
      float av[4] = {a4.x, a4.y, a4.z, a4.w};
      float bv[4] = {b4.x, b4.y, b4.z, b4.w};
      #pragma unroll
      for (int i = 0; i < 4; ++i)
        #pragma unroll
        for (int j = 0; j < 4; ++j)
          acc[i][j] += av[i] * bv[j];
    }
  }
  #pragma unroll
  for (int i = 0; i < 4; ++i)
    #pragma unroll
    for (int j = 0; j < 4; ++j)
      Mb[(ty * 4 + i) * 64 + tx * 4 + j] = acc[i][j];
}

// ---------------------------------------------------------------- WpmT[bc][h*64+d][s] = 0.125*(M^T @ Wp^T) -> split
__global__ __launch_bounds__(256) void wpm_kernel(
    const float* __restrict__ M, const ushort* __restrict__ WpTh, const ushort* __restrict__ WpTl,
    ushort* __restrict__ outH, ushort* __restrict__ outL) {
  int z = blockIdx.y, h = z & 7;
  int s0 = blockIdx.x * 128;
  __shared__ float sM[64][65];    // sM[e][d]
  __shared__ float sW[64][132];   // sW[e][s]
  int tid = threadIdx.x;
  const float* Mb = M + (i64)z * 4096;
  for (int i = 0; i < 16; ++i) {
    int idx = i * 256 + tid;
    sM[idx >> 6][idx & 63] = Mb[idx];
  }
  for (int i = 0; i < 32; ++i) {
    int idx = i * 256 + tid;
    int e = idx >> 7, s = idx & 127;
    i64 g = (i64)(h * 64 + e) * 512 + s0 + s;
    sW[e][s] = __uint_as_float((unsigned)WpTh[g] << 16) +
               __uint_as_float((unsigned)WpTl[g] << 16);
  }
  __syncthreads();
  i64 obase = (i64)(z >> 3) * ((i64)FULL * FULL) + (i64)(h * 64) * 512 + s0;
  for (int i = 0; i < 32; ++i) {
    int idx = i * 256 + tid;
    int d = idx >> 7, s = idx & 127;
    float a = 0.f;
    #pragma unroll
    for (int e = 0; e < 64; ++e) a += sM[e][d] * sW[e][s];
    float v = 0.125f * a;
    i64 o = obase + (i64)d * 512 + s;
    ushort hh = f32_to_bf16_rtn(v);
    outH[o] = hh;
    outL[o] = f32_to_bf16_rtn(v - __uint_as_float((unsigned)hh << 16));
  }
}

// ---------------------------------------------------------------- fused bias2[bc][col] = 0.125*bp@M + bpi
__global__ __launch_bounds__(256) void bias2_kernel(
    const float* __restrict__ M, const float* __restrict__ bp,
    const float* __restrict__ bpi, float* __restrict__ b2) {
  int idx = blockIdx.x * 256 + threadIdx.x;
  if (idx >= NBC * FULL) return;
  int bc = idx >> 9, col = idx & 511;
  int h = col >> 6, d = col & 63;
  const float* Mb = M + ((i64)(bc * 8 + h)) * 4096;
  float s = 0.f;
  for (int e = 0; e < 64; ++e) s += bp[h * 64 + e] * Mb[e * 64 + d];
  b2[idx] = 0.125f * s + bpi[col];
}

// ---------------------------------------------------------------- MFMA flash attention v4: Q in regs, dbuf K/V, 1 barrier/step
// per-buffer: KH 8KB @ b*24576, KL @ +8192, VH @ +16384; P @ 49152
__global__ __launch_bounds__(256, 2) void attn4_kernel(
    const ushort* __restrict__ Qh, const ushort* __restrict__ Ql,
    const ushort* __restrict__ Kh, const ushort* __restrict__ Kl,
    const ushort* __restrict__ Vh, float* __restrict__ out) {
  int z = blockIdx.y;
  int qt = 3 - (int)blockIdx.x;          // longest blocks first
  int bc = z >> 3, h = z & 7;
  __shared__ __align__(16) char lds[65536];
  int tid = threadIdx.x, lane = tid & 63, wid = tid >> 6;
  int fr = lane & 15, fg = lane >> 4;
  int swz = (fr & 7) << 4;

  const i64 IMG2 = 262144;
  const char* bQh = (const char*)(Qh + (i64)bc * IMG2) + (i64)(qt * 128) * 1024 + h * 128;
  const char* bQl = (const char*)(Ql + (i64)bc * IMG2) + (i64)(qt * 128) * 1024 + h * 128;
  const char* bKh = (const char*)(Kh + (i64)bc * IMG2) + h * 128;
  const char* bKl = (const char*)(Kl + (i64)bc * IMG2) + h * 128;
  const char* bVT = (const char*)(Vh + (i64)bc * IMG2) + (i64)(h * 64) * 1024;

  // ---- Q fragments -> registers (once) ----
  bf16x8 qh[2][2], ql[2][2];   // [qf][ks]
  #pragma unroll
  for (int qf = 0; qf < 2; ++qf)
    #pragma unroll
    for (int ks = 0; ks < 2; ++ks) {
      i64 off = (i64)(wid * 32 + qf * 16 + fr) * 1024 + ks * 64 + fg * 16;
      qh[qf][ks] = *(const bf16x8*)(bQh + off);
      ql[qf][ks] = *(const bf16x8*)(bQl + off);
    }

  int srow = tid >> 3, scolb = (tid & 7) * 16;
  int nst = 2 * qt + 2;

  float m_i[2][4], l_i[2][4];
  f32x4 acc[2][4] = {};
  #pragma unroll
  for (int qf = 0; qf < 2; ++qf)
    #pragma unroll
    for (int q = 0; q < 4; ++q) { m_i[qf][q] = -3e38f; l_i[qf][q] = 0.f; }

  // prologue: stage tile 0 into buffer 0
  {
    #pragma unroll
    for (int i = 0; i < 2; ++i) {
      int rr = i * 32 + srow;
      int cc = scolb ^ ((rr & 7) << 4);
      char* base = lds + i * 4096 + wid * 1024;
      gload_lds16(bKh + (i64)rr * 1024 + cc, base);
      gload_lds16(bKl + (i64)rr * 1024 + cc, base + 8192);
      gload_lds16(bVT + (i64)rr * 1024 + cc, base + 16384);
    }
  }

  for (int st = 0; st < nst; ++st) {
    __syncthreads();   // drains vmcnt: tile st ready; prior reads of buf^1 done
    if (st + 1 < nst) {
      int b = (st + 1) & 1;
      #pragma unroll
      for (int i = 0; i < 2; ++i) {
        int rr = i * 32 + srow;
        int cc = scolb ^ ((rr & 7) << 4);
        char* base = lds + b * 24576 + i * 4096 + wid * 1024;
        gload_lds16(bKh + (i64)((st + 1) * 64 + rr) * 1024 + cc, base);
        gload_lds16(bKl + (i64)((st + 1) * 64 + rr) * 1024 + cc, base + 8192);
        gload_lds16(bVT + (i64)rr * 1024 + (st + 1) * 128 + cc, base + 16384);
      }
    }
    const char* B = lds + (st & 1) * 24576;

    // ---- S = Q @ K^T (3-MFMA split) ----
    f32x4 sv[2][4] = {};
    __builtin_amdgcn_s_setprio(1);
    #pragma unroll
    for (int ks = 0; ks < 2; ++ks) {
      int ko = (ks * 64 + fg * 16) ^ swz;
      #pragma unroll
      for (int f = 0; f < 4; ++f) {
        bf16x8 bH = *(const bf16x8*)(B + (f * 16 + fr) * 128 + ko);
        bf16x8 bL = *(const bf16x8*)(B + 8192 + (f * 16 + fr) * 128 + ko);
        #pragma unroll
        for (int qf = 0; qf < 2; ++qf) {
          sv[qf][f] = __builtin_amdgcn_mfma_f32_16x16x32_bf16(qh[qf][ks], bH, sv[qf][f], 0, 0, 0);
          sv[qf][f] = __builtin_amdgcn_mfma_f32_16x16x32_bf16(qh[qf][ks], bL, sv[qf][f], 0, 0, 0);
          sv[qf][f] = __builtin_amdgcn_mfma_f32_16x16x32_bf16(ql[qf][ks], bH, sv[qf][f], 0, 0, 0);
        }
      }
    }
    __builtin_amdgcn_s_setprio(0);

    // ---- scale + causal mask ----
    #pragma unroll
    for (int qf = 0; qf < 2; ++qf)
      #pragma unroll
      for (int f = 0; f < 4; ++f)
        #pragma unroll
        for (int q = 0; q < 4; ++q) {
          float x = sv[qf][f][q] * 0.125f;
          if (st >= 2 * qt) {
            int gq = qt * 128 + wid * 32 + qf * 16 + fg * 4 + q;
            int gk = st * 64 + f * 16 + fr;
            if (gk > gq) x = -3e38f;
          }
          sv[qf][f][q] = x;
        }

    // ---- online softmax ----
    float rm[2][4];
    #pragma unroll
    for (int qf = 0; qf < 2; ++qf)
      #pragma unroll
      for (int q = 0; q < 4; ++q)
        rm[qf][q] = fmaxf(fmaxf(sv[qf][0][q], sv[qf][1][q]), fmaxf(sv[qf][2][q], sv[qf][3][q]));
    #pragma unroll
    for (int off = 8; off >= 1; off >>= 1)
      #pragma unroll
      for (int qf = 0; qf < 2; ++qf)
        #pragma unroll
        for (int q = 0; q < 4; ++q)
          rm[qf][q] = fmaxf(rm[qf][q], __shfl_xor(rm[qf][q], off));

    float alpha[2][4], rs[2][4], pv[2][4][4];
    #pragma unroll
    for (int qf = 0; qf < 2; ++qf)
      #pragma unroll
      for (int q = 0; q < 4; ++q) {
        float mn = fmaxf(m_i[qf][q], rm[qf][q]);
        alpha[qf][q] = __expf(m_i[qf][q] - mn);
        m_i[qf][q] = mn;
        rs[qf][q] = 0.f;
        #pragma unroll
        for (int f = 0; f < 4; ++f) {
          float p = __expf(sv[qf][f][q] - mn);
          pv[qf][f][q] = p;
          rs[qf][q] += p;
        }
      }
    #pragma unroll
    for (int off = 8; off >= 1; off >>= 1)
      #pragma unroll
      for (int qf = 0; qf < 2; ++qf)
        #pragma unroll
        for (int q = 0; q < 4; ++q)
          rs[qf][q] += __shfl_xor(rs[qf][q], off);
    #pragma unroll
    for (int qf = 0; qf < 2; ++qf)
      #pragma unroll
      for (int q = 0; q < 4; ++q) {
        l_i[qf][q] = l_i[qf][q] * alpha[qf][q] + rs[qf][q];
        #pragma unroll
        for (int fd = 0; fd < 4; ++fd)
          acc[qf][fd][q] *= alpha[qf][q];
      }

    // ---- P -> LDS bf16 (wave-private rows) ----
    #pragma unroll
    for (int qf = 0; qf < 2; ++qf)
      #pragma unroll
      for (int f = 0; f < 4; ++f)
        #pragma unroll
        for (int q = 0; q < 4; ++q) {
          int tl = wid * 32 + qf * 16 + fg * 4 + q;
          *(ushort*)(lds + 49152 + tl * 128 + ((f * 32 + fr * 2) ^ ((tl & 7) << 4))) =
              f32_to_bf16_rtn(pv[qf][f][q]);
        }

    // ---- O += P @ V (V hi only) ----
    __builtin_amdgcn_s_setprio(1);
    #pragma unroll
    for (int ks = 0; ks < 2; ++ks) {
      int ko = (ks * 64 + fg * 16) ^ swz;
      bf16x8 pa[2];
      #pragma unroll
      for (int qf = 0; qf < 2; ++qf)
        pa[qf] = *(const bf16x8*)(lds + 49152 + (wid * 32 + qf * 16 + fr) * 128 + ko);
      #pragma unroll
      for (int fd = 0; fd < 4; ++fd) {
        bf16x8 vh = *(const bf16x8*)(B + 16384 + (fd * 16 + fr) * 128 + ko);
        #pragma unroll
        for (int qf = 0; qf < 2; ++qf)
          acc[qf][fd] = __builtin_amdgcn_mfma_f32_16x16x32_bf16(pa[qf], vh, acc[qf][fd], 0, 0, 0);
      }
    }
    __builtin_amdgcn_s_setprio(0);
  }

  // ---- epilogue ----
  #pragma unroll
  for (int qf = 0; qf < 2; ++qf)
    #pragma unroll
    for (int q = 0; q < 4; ++q) {
      float inv = 1.f / l_i[qf][q];
      int t = qt * 128 + wid * 32 + qf * 16 + fg * 4 + q;
      #pragma unroll
      for (int fd = 0; fd < 4; ++fd)
        out[((i64)bc * FULL + t) * FULL + h * 64 + fd * 16 + fr] = acc[qf][fd][q] * inv;
    }
}

// ---------------------------------------------------------------- launch
extern "C" void kernel_launch(void* const* d_in, const int* in_sizes, int n_in,
                              void* d_out, int out_size, void* d_ws, size_t ws_size,
                              hipStream_t stream) {
  const float* idx_i  = (const float*)d_in[0];
  const float* idx_t  = (const float*)d_in[1];
  const float* idx_ir = (const float*)d_in[2];
  const float* Wli = (const float*)d_in[3];
  const float* bli = (const float*)d_in[4];
  const float* Wlt = (const float*)d_in[5];
  const float* blt = (const float*)d_in[6];
  const float* Wlir = (const float*)d_in[7];
  const float* blir = (const float*)d_in[8];
  const float* Wlo = (const float*)d_in[9];
  const float* blo = (const float*)d_in[10];
  const float* Wp  = (const float*)d_in[11];
  const float* bp  = (const float*)d_in[12];
  const float* Wk  = (const float*)d_in[13];
  const float* bk  = (const float*)d_in[14];
  const float* Wpi = (const float*)d_in[15];
  const float* bpi = (const float*)d_in[16];
  const float* Wki = (const float*)d_in[17];
  const float* bki = (const float*)d_in[18];
  const float* Wv  = (const float*)d_in[19];
  const float* bv  = (const float*)d_in[20];

  const i64 PL = (i64)NBC * FULL * FULL;      // plane slab (ushorts)
  const i64 WPL = (i64)FULL * FULL;
  const i64 AS = (i64)FULL * FULL;
  ushort* U = (ushort*)d_ws;
  ushort* s0 = U;            ushort* s1 = U + PL;
  ushort* s2 = U + 2 * PL;   ushort* s3 = U + 3 * PL;
  ushort* s4 = U + 4 * PL;   ushort* s5 = U + 5 * PL;
  ushort* s6 = U + 6 * PL;   ushort* s7 = U + 7 * PL;
  ushort* wreg = U + 8 * PL;
  float* Mbuf = (float*)(wreg + 16 * WPL);
  float* bias2 = Mbuf + (i64)192 * 4096;
  ushort* D0 = (ushort*)d_out;       // d_out scratch (2 plane slots), dead before attn
  ushort* D1 = D0 + PL;
  float* keyF = (float*)s4;          // key fp32 occupies slots 4,5

  dim3 blk(256);

  auto mk = [](const ushort* Ah, const ushort* Al, const ushort* Bh, const ushort* Bl,
               const float* bias, i64 biasStride,
               float* Cf, ushort* Chi, ushort* Clo,
               i64 aStride, i64 bStride, i64 cStride, int bMod, int transC, int split3) {
    GDesc d; d.Ah = Ah; d.Al = Al; d.Bh = Bh; d.Bl = Bl; d.bias = bias;
    d.biasStride = biasStride; d.Cf = Cf; d.Chi = Chi; d.Clo = Clo;
    d.aStride = aStride; d.bStride = bStride; d.cStride = cStride;
    d.bMod = bMod; d.transC = transC; d.split3 = split3;
    return d;
  };

  // ---- weight prep ----
  transposeSplitW4<<<dim3(8, 8, 4), blk, 0, stream>>>(Wli, Wlt, Wlir, Wlo, wreg, 0);
  transposeSplitW4<<<dim3(1, 8, 32), blk, 0, stream>>>(Wk, Wki, Wp, Wv, wreg, 1);

  // ---- input splits: x->(0,1), idx_t->(2,3), idx_ir->(4,5) ----
  add3_split<<<2048, blk, 0, stream>>>((const float4*)idx_i, (const float4*)idx_t,
                                       (const float4*)idx_ir,
                                       (ushort4*)s0, (ushort4*)s1,
                                       (ushort4*)s2, (ushort4*)s3,
                                       (ushort4*)s4, (ushort4*)s5, (int)(PL / 4));

  // G1: xt = idx_t@Wlt -> (6,7) | xir = idx_ir@Wlir -> (D0,D1)
  gemm_m<<<dim3(4, 4, 48), blk, 0, stream>>>(
      mk(s2, s3, wreg + 2 * WPL, wreg + 3 * WPL, blt, 0, nullptr, s6, s7, AS, 0, AS, 1, 0, 1),
      mk(s4, s5, wreg + 4 * WPL, wreg + 5 * WPL, blir, 0, nullptr, D0, D1, AS, 0, AS, 1, 0, 1), 24);
  // G2: xi = x@Wli -> (2,3) | key = xt@Wk -> fp32 (4,5)
  gemm_m<<<dim3(4, 4, 48), blk, 0, stream>>>(
      mk(s0, s1, wreg + 0 * WPL, wreg + 1 * WPL, bli, 0, nullptr, s2, s3, AS, 0, AS, 1, 0, 1),
      mk(s6, s7, wreg + 8 * WPL, wreg + 9 * WPL, bk, 0, keyF, nullptr, nullptr, AS, 0, AS, 1, 0, 1), 24);
  // M = key^T @ Wpi
  mh_kernel<<<192, blk, 0, stream>>>(keyF, Wpi, Mbuf);
  // bias2 = 0.125*bp@M + bpi
  bias2_kernel<<<48, blk, 0, stream>>>(Mbuf, bp, bpi, bias2);
  // xt -> xtT in place (6,7)   [key dead after mh]
  transposeIP<<<dim3(8, 8, 48), blk, 0, stream>>>(s6, s7, AS);
  // G3: t1 = xi@xtT -> (4,5) | keyi = xir@Wki -> (0,1)
  gemm_m<<<dim3(4, 4, 48), blk, 0, stream>>>(
      mk(s2, s3, s6, s7, nullptr, 0, nullptr, s4, s5, AS, AS, AS, NBC, 0, 1),
      mk(D0, D1, wreg + 10 * WPL, wreg + 11 * WPL, bki, 0, nullptr, s0, s1, AS, 0, AS, 1, 0, 1), 24);
  // xir -> xirT in place (D0,D1)
  transposeIP<<<dim3(8, 8, 48), blk, 0, stream>>>(D0, D1, AS);
  // G4: t2 = t1@xirT -> (2,3)   [xi dead]
  {
    GDesc dt2 = mk(s4, s5, D0, D1, nullptr, 0, nullptr, s2, s3, AS, AS, AS, NBC, 0, 1);
    gemm_m<<<dim3(4, 4, 24), blk, 0, stream>>>(dt2, dt2, 24);
  }
  // WpmT = 0.125 * M^T @ Wp^T -> (D0,D1)   [xirT dead]
  wpm_kernel<<<dim3(4, 192), blk, 0, stream>>>(Mbuf, wreg + 12 * WPL, wreg + 13 * WPL, D0, D1);
  // G5: xi2 = t2@Wlo -> (4,5)   [t1 dead]
  {
    GDesc dx2 = mk(s2, s3, wreg + 6 * WPL, wreg + 7 * WPL, blo, 0, nullptr, s4, s5, AS, 0, AS, 1, 0, 1);
    gemm_m<<<dim3(4, 4, 24), blk, 0, stream>>>(dx2, dx2, 24);
  }
  // G6: q2 = xi2@WpmT + bias2 -> (2,3) | valT = xi2@Wv + bv (hi, transposed) -> (6)
  gemm_m<<<dim3(4, 4, 48), blk, 0, stream>>>(
      mk(s4, s5, D0, D1, bias2, 512, nullptr, s2, s3, AS, AS, AS, NBC, 0, 1),
      mk(s4, s5, wreg + 14 * WPL, wreg + 15 * WPL, bv, 0, nullptr, s6, nullptr, AS, 0, AS, 1, 1, 0), 24);
  // attention: Q(2,3), K(0,1), V^T(6) -> d_out   [D0,D1 dead]
  attn4_kernel<<<dim3(4, 192), blk, 0, stream>>>(s2, s3, s0, s1, s6, (float*)d_out);
}